// Round 16
// baseline (232.703 us; speedup 1.0000x reference)
//
#include <hip/hip_runtime.h>
#include <hip/hip_bf16.h>

constexpr int Dd   = 512;
constexpr int Nn   = 1024;
constexpr int Ttok = 16384;              // B*L
constexpr float DECAYc = 0.99f;
// Coarse scores are f32 MFMA of bf16-rounded inputs: error std ~0.07.
// GAP=3.0 on the EXACT coarse runner-up (top-3 store makes g1 exact).
constexpr float GAP = 3.0f;
constexpr int CH = 16;                   // tokens per dw chunk

typedef short bf16x8 __attribute__((ext_vector_type(8)));
typedef float f32x4  __attribute__((ext_vector_type(4)));

__device__ inline unsigned cvtpk(float lo, float hi) { // 2xf32 -> packed bf16
  unsigned r;
  asm("v_cvt_pk_bf16_f32 %0, %1, %2" : "=v"(r) : "v"(lo), "v"(hi));
  return r;
}

// ---- fused prep: cb->bf16 + csq (blocks 0..255), zero dw/hist/terms
// (blocks 256..287), x->bf16 + Sxx partial sums (blocks 288..2335)
constexpr int NB_CB = 256, NB_Z = 32, NB_X = 2048;
constexpr int ZF4 = 131329;              // float4s to zero (dw+hist+terms)
__global__ __launch_bounds__(256) void k_prep(
    const float* __restrict__ cb, const float* __restrict__ x,
    unsigned short* __restrict__ cbh, float* __restrict__ csq,
    unsigned short* __restrict__ xh, float4* __restrict__ zbase,
    float* __restrict__ Sxx) {
  const int b = blockIdx.x, tid = threadIdx.x;
  if (b < NB_CB) {
    const int n = b * 4 + (tid >> 6), l = tid & 63;
    const float4* r = (const float4*)(cb + (size_t)n * Dd);
    float4 a = r[l], c = r[l + 64];
    float ss = a.x*a.x + a.y*a.y + a.z*a.z + a.w*a.w
             + c.x*c.x + c.y*c.y + c.z*c.z + c.w*c.w;
    uint2 ua, uc;
    ua.x = cvtpk(a.x, a.y); ua.y = cvtpk(a.z, a.w);
    uc.x = cvtpk(c.x, c.y); uc.y = cvtpk(c.z, c.w);
    ((uint2*)(cbh + (size_t)n * Dd))[l]      = ua;
    ((uint2*)(cbh + (size_t)n * Dd))[l + 64] = uc;
#pragma unroll
    for (int o = 32; o; o >>= 1) ss += __shfl_down(ss, o);
    if (l == 0) csq[n] = ss;
  } else if (b < NB_CB + NB_Z) {
    const float4 z = make_float4(0.f, 0.f, 0.f, 0.f);
    for (int i = (b - NB_CB) * 256 + tid; i < ZF4; i += NB_Z * 256)
      zbase[i] = z;
  } else {
    const int bx = b - (NB_CB + NB_Z);
    float sx = 0.f;
#pragma unroll
    for (int k = 0; k < 2; ++k) {
      const int i = bx * 512 + k * 256 + tid;     // 8-float chunk id
      float4 a = ((const float4*)x)[i * 2];
      float4 c = ((const float4*)x)[i * 2 + 1];
      sx += a.x*a.x + a.y*a.y + a.z*a.z + a.w*a.w
          + c.x*c.x + c.y*c.y + c.z*c.z + c.w*c.w;
      uint4 o;
      o.x = cvtpk(a.x, a.y); o.y = cvtpk(a.z, a.w);
      o.z = cvtpk(c.x, c.y); o.w = cvtpk(c.z, c.w);
      ((uint4*)xh)[i] = o;
    }
#pragma unroll
    for (int o = 32; o; o >>= 1) sx += __shfl_down(sx, o);
    if ((tid & 63) == 0) atomicAdd(Sxx, sx);      // fire-and-forget
  }
}

// ------------- MFMA GEMM, BK=32 (r13-proven): both operands via
// global_load_lds, double-buffered, ONE barrier per K-step; 32 KB LDS ->
// 5 blocks/CU; 64B rows = natural conflict-free reads, linear lds dest.
// Fused per-64-code-half top-3 argmin epilogue (v0,v1,i0|i1,v2).
__global__ __launch_bounds__(256) void k_gemm_scores(
    const unsigned short* __restrict__ cbh, const unsigned short* __restrict__ xh,
    const float* __restrict__ csq, float4* __restrict__ part) {
  __shared__ unsigned short As[2][128 * 32];   // codes  (8 KB x2)
  __shared__ unsigned short Bs[2][128 * 32];   // tokens (8 KB x2)
  const int tid = threadIdx.x;
  const int w = tid >> 6, l = tid & 63;
  const int b = blockIdx.x;
  const int s = (b & 7) * 128 + (b >> 3);      // XCD-aware bijective swizzle
  const int cm = s & 7;        // code-block  (M)
  const int tn = s >> 3;       // token-block (N)
  const int wr = w >> 1, wc = w & 1;

  const int srow = tid >> 2;                   // 0..63 staging row
  const int scol = (tid & 3) * 8;              // elem offset of 16B chunk

  f32x4 acc[4][4] = {};

  const unsigned short* gA0 = cbh + (size_t)(cm * 128) * Dd;
  const unsigned short* gB0 = xh  + (size_t)(tn * 128) * Dd;

#define ISSUE(KC, BUF) do {                                                   \
    const int k0_ = (KC) * 32;                                                \
    _Pragma("unroll")                                                         \
    for (int p = 0; p < 2; ++p) {                                             \
      const unsigned short* ga = gA0 + (size_t)(p * 64 + srow) * Dd + k0_ + scol; \
      const unsigned short* gb = gB0 + (size_t)(p * 64 + srow) * Dd + k0_ + scol; \
      char* la = (char*)&As[BUF][0] + p * 4096 + w * 1024;                    \
      char* lb = (char*)&Bs[BUF][0] + p * 4096 + w * 1024;                    \
      __builtin_amdgcn_global_load_lds((const __attribute__((address_space(1))) void*)ga, \
                                       (__attribute__((address_space(3))) void*)la, 16, 0, 0); \
      __builtin_amdgcn_global_load_lds((const __attribute__((address_space(1))) void*)gb, \
                                       (__attribute__((address_space(3))) void*)lb, 16, 0, 0); \
    }                                                                         \
  } while (0)

  ISSUE(0, 0);

  for (int kc = 0; kc < Dd / 32; ++kc) {
    __syncthreads();      // drains vmem -> tile kc ready; syncs buffer reuse
    if (kc + 1 < Dd / 32) ISSUE(kc + 1, (kc + 1) & 1);   // lands next barrier
    const unsigned short* Ab = &As[kc & 1][0];
    const unsigned short* Bb = &Bs[kc & 1][0];
    const int ra = l & 15;
    const int kb = (l >> 4) * 8;               // 4 chunks spread across lanes
    bf16x8 af[4], bfr[4];
#pragma unroll
    for (int m = 0; m < 4; ++m)
      af[m] = *(const bf16x8*)&Ab[(wr * 64 + m * 16 + ra) * 32 + kb];
#pragma unroll
    for (int n = 0; n < 4; ++n)
      bfr[n] = *(const bf16x8*)&Bb[(wc * 64 + n * 16 + ra) * 32 + kb];
#pragma unroll
    for (int m = 0; m < 4; ++m)
#pragma unroll
      for (int n = 0; n < 4; ++n)
        acc[m][n] = __builtin_amdgcn_mfma_f32_16x16x32_bf16(af[m], bfr[n], acc[m][n], 0, 0, 0);
  }
#undef ISSUE

  // ------- fused per-half top-3 epilogue -------
  const int base4 = wr * 64 + (l >> 4) * 4;      // lane's local code base
  float4 cs[4];
#pragma unroll
  for (int m = 0; m < 4; ++m)
    cs[m] = *(const float4*)&csq[cm * 128 + base4 + m * 16];

  const int slot = cm * 2 + wr;                  // 0..15
  const int tok0 = tn * 128 + wc * 64 + (l & 15);

#pragma unroll
  for (int n = 0; n < 4; ++n) {
    float v0 = 3.4e38f, v1 = 3.4e38f, v2 = 3.4e38f;
    int i0 = 0x7fffffff, i1 = 0x7fffffff;
#pragma unroll
    for (int m = 0; m < 4; ++m) {
#pragma unroll
      for (int r = 0; r < 4; ++r) {
        float sv = fmaf(-2.0f, acc[m][n][r], ((const float*)&cs[m])[r]);
        int idx = cm * 128 + base4 + m * 16 + r;
        if (sv < v0)      { v2 = v1; v1 = v0; i1 = i0; v0 = sv; i0 = idx; }
        else if (sv < v1) { v2 = v1; v1 = sv; i1 = idx; }
        else if (sv < v2) { v2 = sv; }
      }
    }
#pragma unroll
    for (int o = 16; o <= 32; o <<= 1) {
      float w0 = __shfl_xor(v0, o), w1 = __shfl_xor(v1, o), w2 = __shfl_xor(v2, o);
      int  j0 = __shfl_xor(i0, o), j1 = __shfl_xor(i1, o);
      bool f = (w0 < v0) || (w0 == v0 && j0 < i0);
      float A0 = f ? w0 : v0, A1 = f ? w1 : v1, A2 = f ? w2 : v2;
      int  Ai0 = f ? j0 : i0, Ai1 = f ? j1 : i1;
      float B0 = f ? v0 : w0, B1 = f ? v1 : w1;
      int  Bi0 = f ? i0 : j0;
      bool g = (A1 < B0) || (A1 == B0 && Ai1 < Bi0);
      v0 = A0; i0 = Ai0;
      v1 = g ? A1 : B0; i1 = g ? Ai1 : Bi0;
      v2 = g ? fminf(A2, B0) : fminf(A1, B1);
    }
    if ((l >> 4) == 0)
      part[(size_t)slot * Ttok + tok0 + n * 16] = make_float4(
          v0, v1, __uint_as_float((unsigned)i0 | ((unsigned)i1 << 16)), v2);
  }
}

// exact fp32 rescore of one code (wave-cooperative), uniform n
__device__ inline void rescore(int n, const float4& xa, const float4& xb,
                               const float* __restrict__ cb,
                               const float* __restrict__ csq, int l,
                               float& bestv, int& besti) {
  const float4* cr = (const float4*)(cb + (size_t)n * Dd);
  float4 ca = cr[l * 2], cc = cr[l * 2 + 1];
  float p = xa.x*ca.x + xa.y*ca.y + xa.z*ca.z + xa.w*ca.w
          + xb.x*cc.x + xb.y*cc.y + xb.z*cc.z + xb.w*cc.w;
#pragma unroll
  for (int o = 32; o; o >>= 1) p += __shfl_xor(p, o);
  float sc = csq[n] - 2.0f * p;
  if (sc < bestv || (sc == bestv && n < besti)) { bestv = sc; besti = n; }
}

// exact rescore of a full 64-code half: one code per lane, then wave-argmin
__device__ inline void rescore_half(int h, const float* __restrict__ xrow,
                                    const float* __restrict__ cb,
                                    const float* __restrict__ csq, int l,
                                    float& bestv, int& besti) {
  int n = h * 64 + l;
  const float4* cr = (const float4*)(cb + (size_t)n * Dd);
  const float4* xr = (const float4*)xrow;
  float p = 0.f;
#pragma unroll 8
  for (int j = 0; j < 128; ++j) {
    float4 c4 = cr[j], x4 = xr[j];
    p += c4.x*x4.x + c4.y*x4.y + c4.z*x4.z + c4.w*x4.w;
  }
  float sc = csq[n] - 2.0f * p;
#pragma unroll
  for (int o = 1; o < 64; o <<= 1) {
    float ov = __shfl_xor(sc, o); int oi = __shfl_xor(n, o);
    if (ov < sc || (ov == sc && oi < n)) { sc = ov; n = oi; }
  }
  if (sc < bestv || (sc == bestv && n < besti)) { bestv = sc; besti = n; }
}

// ---- per-token: merge 16 half partials; fast path when exact coarse
// runner-up trails min by > GAP (no loads); else rescore candidates.
// NOTE (r14/r15 lesson): hist atomic stays fire-and-forget — NO barrier
// or waitcnt after any contended atomic.
__global__ __launch_bounds__(256) void k_select(
    const float4* __restrict__ part, const float* __restrict__ x,
    const float* __restrict__ cb, const float* __restrict__ csq,
    int* __restrict__ idxb, float* __restrict__ idxf, float* __restrict__ hist) {
  const int tid = threadIdx.x, wid = tid >> 6, l = tid & 63;
  const int t = blockIdx.x * 4 + wid;
  float v0 = 3.4e38f, v1 = 3.4e38f, v2 = 3.4e38f;
  int i0 = 0x7fffffff, i1 = 0x7fffffff;
  if (l < 16) {
    float4 e = part[(size_t)l * Ttok + t];
    v0 = e.x; v1 = e.y; v2 = e.w;
    unsigned ii = __float_as_uint(e.z);
    i0 = (int)(ii & 0xffff); i1 = (int)(ii >> 16);
  }
  float A0 = v0, A1 = v1; int Ai0 = i0, Ai1 = i1;
#pragma unroll
  for (int o = 1; o < 16; o <<= 1) {
    float w0 = __shfl_xor(A0, o), w1 = __shfl_xor(A1, o);
    int  j0 = __shfl_xor(Ai0, o), j1 = __shfl_xor(Ai1, o);
    bool f = (w0 < A0) || (w0 == A0 && j0 < Ai0);
    float B0 = f ? A0 : w0; int Bi0 = f ? Ai0 : j0;
    float W1 = f ? w1 : A1; int Wi1 = f ? j1 : Ai1;
    if (f) { A0 = w0; Ai0 = j0; }
    bool g = (B0 < W1) || (B0 == W1 && Bi0 < Wi1);
    A1 = g ? B0 : W1; Ai1 = g ? Bi0 : Wi1;
  }
  const float m  = __shfl(A0, 0);
  const float g1 = __shfl(A1, 0);
  const int   gi = __shfl(Ai0, 0);
  int besti;
  if (g1 - m > GAP) {
    besti = gi;
  } else {
    const float thr = m + GAP;
    const float* xrow = x + (size_t)t * Dd;
    const float4* xr = (const float4*)xrow;
    float4 xa = xr[l * 2], xb = xr[l * 2 + 1];
    float bestv = 3.4e38f; besti = 0x7fffffff;
    for (int h = 0; h < 16; ++h) {
      float b0 = __shfl(v0, h);
      if (b0 > thr) continue;
      float b1 = __shfl(v1, h), b2 = __shfl(v2, h);
      int bi0 = __shfl(i0, h), bi1 = __shfl(i1, h);
      if (b2 <= thr) {
        rescore_half(h, xrow, cb, csq, l, bestv, besti);
      } else {
        rescore(bi0, xa, xb, cb, csq, l, bestv, besti);
        if (b1 <= thr) rescore(bi1, xa, xb, cb, csq, l, bestv, besti);
      }
    }
  }
  if (l == 0) {
    idxb[t] = besti;
    idxf[t] = (float)besti;
    atomicAdd(&hist[besti], 1.0f);
  }
}

// ----------------- prefix sum of histogram (1 block, 256 thr, wave scan)
__global__ __launch_bounds__(256) void k_offsets(const float* __restrict__ hist,
                                                 int* __restrict__ cursor) {
  __shared__ int wsum[4];
  const int tid = threadIdx.x, l = tid & 63, wd = tid >> 6;
  const int base = tid * 4;
  int c0 = (int)hist[base], c1 = (int)hist[base + 1],
      c2 = (int)hist[base + 2], c3 = (int)hist[base + 3];
  int sum = c0 + c1 + c2 + c3;
  int sc = sum;
#pragma unroll
  for (int o = 1; o < 64; o <<= 1) { int v = __shfl_up(sc, o); if (l >= o) sc += v; }
  if (l == 63) wsum[wd] = sc;
  __syncthreads();
  int wbase = 0;
  for (int i = 0; i < wd; ++i) wbase += wsum[i];
  int e = wbase + sc - sum;
  cursor[base]     = e;
  cursor[base + 1] = e + c0;
  cursor[base + 2] = e + c0 + c1;
  cursor[base + 3] = e + c0 + c1 + c2;
}

// -------------------------------- bucket tokens by index (code-sorted order)
__global__ __launch_bounds__(256) void k_scatter(const int* __restrict__ idxb,
                                                 int* __restrict__ cursor,
                                                 int* __restrict__ bucket,
                                                 int* __restrict__ bcode) {
  int t = blockIdx.x * 256 + threadIdx.x;
  if (t < Ttok) {
    int n = idxb[t];
    int p = atomicAdd(&cursor[n], 1);
    bucket[p] = t;
    bcode[p] = n;
  }
}

// ------- load-balanced segmented sum: dw[n][d] += x rows of chunk segments
__global__ __launch_bounds__(512) void k_dw_part(
    const float* __restrict__ x, const int* __restrict__ bucket,
    const int* __restrict__ bcode, float* __restrict__ dw) {
  __shared__ int sh_t[CH], sh_n[CH];
  const int tid = threadIdx.x;
  const int p0 = blockIdx.x * CH;
  if (tid < CH) { sh_t[tid] = bucket[p0 + tid]; sh_n[tid] = bcode[p0 + tid]; }
  __syncthreads();
  float v[CH];
#pragma unroll
  for (int j = 0; j < CH; ++j)
    v[j] = x[(size_t)sh_t[j] * Dd + tid];
  float acc = v[0]; int cur = sh_n[0];
#pragma unroll
  for (int j = 1; j < CH; ++j) {
    int n = sh_n[j];
    if (n != cur) { atomicAdd(&dw[(size_t)cur * Dd + tid], acc); acc = 0.f; cur = n; }
    acc += v[j];
  }
  atomicAdd(&dw[(size_t)cur * Dd + tid], acc);
}

// ------- per-code loss terms: Sxq = sum_n q_n . dw_n ; Sqq = sum_n hist_n |q_n|^2
// (2 MB ema + 2 MB dw, L2-resident; 1024 blocks x 128 thr; fire-and-forget atomics)
__global__ __launch_bounds__(128) void k_lossterms(
    const float* __restrict__ ema, const float* __restrict__ dw,
    const float* __restrict__ counts, const float* __restrict__ hist,
    float* __restrict__ Sxq, float* __restrict__ Sqq) {
  const int n = blockIdx.x, tid = threadIdx.x;
  const float hc = hist[n];
  const float inv = 1.0f / (DECAYc * counts[n] + (1.0f - DECAYc) * hc);
  f32x4 e = ((const f32x4*)(ema + (size_t)n * Dd))[tid];
  f32x4 d = ((const f32x4*)(dw  + (size_t)n * Dd))[tid];
  f32x4 q = (DECAYc * e + (1.0f - DECAYc) * d) * inv;
  float xq = q[0]*d[0] + q[1]*d[1] + q[2]*d[2] + q[3]*d[3];
  float qq = q[0]*q[0] + q[1]*q[1] + q[2]*q[2] + q[3]*q[3];
#pragma unroll
  for (int o = 32; o; o >>= 1) { xq += __shfl_down(xq, o); qq += __shfl_down(qq, o); }
  __shared__ float sx[2], sq[2];
  const int wd = tid >> 6, l = tid & 63;
  if (l == 0) { sx[wd] = xq; sq[wd] = qq; }
  __syncthreads();
  if (tid == 0) {
    atomicAdd(Sxq, sx[0] + sx[1]);
    atomicAdd(Sqq, hc * (sq[0] + sq[1]));
  }
}

// ------- quantized = (decay*ema[idx] + (1-decay)*dw[idx]) / cnt[idx]
// Pure gather + stream write: NO x read, NO reduction (loss via identity).
__global__ __launch_bounds__(256) void quant_out(
    const float* __restrict__ ema, const float* __restrict__ dw,
    const float* __restrict__ counts, const float* __restrict__ hist,
    const int* __restrict__ idx, float* __restrict__ out_q) {
  const int e0 = blockIdx.x * 256 + threadIdx.x;
  const int gsz = 524288;                    // 2048 blocks * 256 threads
  int n[4];
#pragma unroll
  for (int j = 0; j < 4; ++j) n[j] = idx[(e0 + j * gsz) >> 7];
  float inv[4];
#pragma unroll
  for (int j = 0; j < 4; ++j)
    inv[j] = 1.0f / (DECAYc * counts[n[j]] + (1.0f - DECAYc) * hist[n[j]]);
  f32x4 e4[4], d4[4];
#pragma unroll
  for (int j = 0; j < 4; ++j) {
    const int e = e0 + j * gsz;
    e4[j] = ((const f32x4*)(ema + (size_t)n[j] * Dd))[e & 127];
    d4[j] = ((const f32x4*)(dw  + (size_t)n[j] * Dd))[e & 127];
  }
#pragma unroll
  for (int j = 0; j < 4; ++j) {
    f32x4 q = (DECAYc * e4[j] + (1.0f - DECAYc) * d4[j]) * inv[j];
    __builtin_nontemporal_store(q, &((f32x4*)out_q)[e0 + j * gsz]);
  }
}

// loss = 0.5/(T*D) * (Sxx - 2*Sxq + Sqq)
__global__ void loss_final(const float* __restrict__ Sxx,
                           const float* __restrict__ Sxq,
                           const float* __restrict__ Sqq,
                           float* __restrict__ out_loss) {
  *out_loss = (*Sxx - 2.0f * *Sxq + *Sqq) * (0.5f / (float)((size_t)Ttok * Dd));
}

// ---------------------------------------------------------------- launch
extern "C" void kernel_launch(void* const* d_in, const int* in_sizes, int n_in,
                              void* d_out, int out_size, void* d_ws, size_t ws_size,
                              hipStream_t stream) {
  const float* x      = (const float*)d_in[0];
  const float* cb     = (const float*)d_in[1];
  const float* ema    = (const float*)d_in[2];
  const float* counts = (const float*)d_in[3];

  float* out      = (float*)d_out;
  float* q_out    = out;
  float* loss_out = out + (size_t)Ttok * Dd;
  float* idxf_out = loss_out + 1;
  // d_out head reuse before quant_out overwrites it:
  //   part: float4[16][16384] = 4 MB at q_out[0 .. 1M floats)
  //   xh:   bf16 x (16.8 MB)   at q_out[2M .. 6.2M floats)   (no overlap)
  float4* part = (float4*)q_out;
  unsigned short* xh = (unsigned short*)(q_out + 2097152);

  // workspace layout (float offsets)
  float* ws = (float*)d_ws;
  unsigned short* cbh = (unsigned short*)ws;           // [0, 262144)  bf16 cb
  float* dw      = ws + 262144;                        // 524288 (zeroed in k_prep)
  float* hist    = ws + 786432;                        // 1024   (zeroed in k_prep)
  float* Sxx     = ws + 787456;                        // zeroed
  float* Sxq     = ws + 787457;                        // zeroed
  float* Sqq     = ws + 787458;                        // zeroed
  float* csq     = ws + 787460;                        // 1024
  int*   cursor  = (int*)(ws + 789508);                // 1024
  int*   bucket  = (int*)(ws + 790532);                // 16384
  int*   bcode   = (int*)(ws + 806916);                // 16384
  int*   idxb    = (int*)(ws + 823300);                // 16384

  k_prep<<<NB_CB + NB_Z + NB_X, 256, 0, stream>>>(cb, x, cbh, csq, xh,
                                                  (float4*)dw, Sxx);
  k_gemm_scores<<<(Nn / 128) * (Ttok / 128), 256, 0, stream>>>(cbh, xh, csq, part);
  k_select<<<Ttok / 4, 256, 0, stream>>>(part, x, cb, csq, idxb, idxf_out, hist);
  k_offsets<<<1, 256, 0, stream>>>(hist, cursor);
  k_scatter<<<Ttok / 256, 256, 0, stream>>>(idxb, cursor, bucket, bcode);
  k_dw_part<<<Ttok / CH, 512, 0, stream>>>(x, bucket, bcode, dw);
  k_lossterms<<<Nn, 128, 0, stream>>>(ema, dw, counts, hist, Sxq, Sqq);
  quant_out<<<2048, 256, 0, stream>>>(ema, dw, counts, hist, idxb, q_out);
  loss_final<<<1, 1, 0, stream>>>(Sxx, Sxq, Sqq, loss_out);
}

// Round 17
// 117.954 us; speedup vs baseline: 1.9728x; 1.9728x over previous
//
#include <hip/hip_runtime.h>
#include <hip/hip_bf16.h>

constexpr int Dd   = 512;
constexpr int Nn   = 1024;
constexpr int Ttok = 16384;              // B*L
constexpr float DECAYc = 0.99f;
// Coarse scores are f32 MFMA of bf16-rounded inputs: error std ~0.07.
// GAP=3.0 on the EXACT coarse runner-up (top-3 store makes g1 exact).
constexpr float GAP = 3.0f;
constexpr int CH = 16;                   // tokens per dw chunk

typedef short bf16x8 __attribute__((ext_vector_type(8)));
typedef float f32x4  __attribute__((ext_vector_type(4)));

__device__ inline unsigned cvtpk(float lo, float hi) { // 2xf32 -> packed bf16
  unsigned r;
  asm("v_cvt_pk_bf16_f32 %0, %1, %2" : "=v"(r) : "v"(lo), "v"(hi));
  return r;
}

// ---- fused prep: cb->bf16 + csq (blocks 0..255), zero dw/hist
// (blocks 256..287), x->bf16 + per-wave Sxx partials (blocks 288..2335).
// NO contended atomics (r16 lesson: 8192 same-address atomicAdds = 110 us
// serialize + zeroing race); per-wave partials to own slots instead.
constexpr int NB_CB = 256, NB_Z = 32, NB_X = 2048;
constexpr int ZF4 = 131328;              // float4s to zero (dw+hist)
__global__ __launch_bounds__(256) void k_prep(
    const float* __restrict__ cb, const float* __restrict__ x,
    unsigned short* __restrict__ cbh, float* __restrict__ csq,
    unsigned short* __restrict__ xh, float4* __restrict__ zbase,
    float* __restrict__ sxxp) {
  const int b = blockIdx.x, tid = threadIdx.x;
  if (b < NB_CB) {
    const int n = b * 4 + (tid >> 6), l = tid & 63;
    const float4* r = (const float4*)(cb + (size_t)n * Dd);
    float4 a = r[l], c = r[l + 64];
    float ss = a.x*a.x + a.y*a.y + a.z*a.z + a.w*a.w
             + c.x*c.x + c.y*c.y + c.z*c.z + c.w*c.w;
    uint2 ua, uc;
    ua.x = cvtpk(a.x, a.y); ua.y = cvtpk(a.z, a.w);
    uc.x = cvtpk(c.x, c.y); uc.y = cvtpk(c.z, c.w);
    ((uint2*)(cbh + (size_t)n * Dd))[l]      = ua;
    ((uint2*)(cbh + (size_t)n * Dd))[l + 64] = uc;
#pragma unroll
    for (int o = 32; o; o >>= 1) ss += __shfl_down(ss, o);
    if (l == 0) csq[n] = ss;
  } else if (b < NB_CB + NB_Z) {
    const float4 z = make_float4(0.f, 0.f, 0.f, 0.f);
    for (int i = (b - NB_CB) * 256 + tid; i < ZF4; i += NB_Z * 256)
      zbase[i] = z;
  } else {
    const int bx = b - (NB_CB + NB_Z);
    float sx = 0.f;
#pragma unroll
    for (int k = 0; k < 2; ++k) {
      const int i = bx * 512 + k * 256 + tid;     // 8-float chunk id
      float4 a = ((const float4*)x)[i * 2];
      float4 c = ((const float4*)x)[i * 2 + 1];
      sx += a.x*a.x + a.y*a.y + a.z*a.z + a.w*a.w
          + c.x*c.x + c.y*c.y + c.z*c.z + c.w*c.w;
      uint4 o;
      o.x = cvtpk(a.x, a.y); o.y = cvtpk(a.z, a.w);
      o.z = cvtpk(c.x, c.y); o.w = cvtpk(c.z, c.w);
      ((uint4*)xh)[i] = o;
    }
#pragma unroll
    for (int o = 32; o; o >>= 1) sx += __shfl_down(sx, o);
    if ((tid & 63) == 0) sxxp[bx * 4 + (tid >> 6)] = sx;   // own slot, no atomic
  }
}

// ------------- MFMA GEMM, BK=32 (r13-proven): both operands via
// global_load_lds, double-buffered, ONE barrier per K-step; 32 KB LDS ->
// 5 blocks/CU; 64B rows = natural conflict-free reads, linear lds dest.
// Fused per-64-code-half top-3 argmin epilogue (v0,v1,i0|i1,v2).
__global__ __launch_bounds__(256) void k_gemm_scores(
    const unsigned short* __restrict__ cbh, const unsigned short* __restrict__ xh,
    const float* __restrict__ csq, float4* __restrict__ part) {
  __shared__ unsigned short As[2][128 * 32];   // codes  (8 KB x2)
  __shared__ unsigned short Bs[2][128 * 32];   // tokens (8 KB x2)
  const int tid = threadIdx.x;
  const int w = tid >> 6, l = tid & 63;
  const int b = blockIdx.x;
  const int s = (b & 7) * 128 + (b >> 3);      // XCD-aware bijective swizzle
  const int cm = s & 7;        // code-block  (M)
  const int tn = s >> 3;       // token-block (N)
  const int wr = w >> 1, wc = w & 1;

  const int srow = tid >> 2;                   // 0..63 staging row
  const int scol = (tid & 3) * 8;              // elem offset of 16B chunk

  f32x4 acc[4][4] = {};

  const unsigned short* gA0 = cbh + (size_t)(cm * 128) * Dd;
  const unsigned short* gB0 = xh  + (size_t)(tn * 128) * Dd;

#define ISSUE(KC, BUF) do {                                                   \
    const int k0_ = (KC) * 32;                                                \
    _Pragma("unroll")                                                         \
    for (int p = 0; p < 2; ++p) {                                             \
      const unsigned short* ga = gA0 + (size_t)(p * 64 + srow) * Dd + k0_ + scol; \
      const unsigned short* gb = gB0 + (size_t)(p * 64 + srow) * Dd + k0_ + scol; \
      char* la = (char*)&As[BUF][0] + p * 4096 + w * 1024;                    \
      char* lb = (char*)&Bs[BUF][0] + p * 4096 + w * 1024;                    \
      __builtin_amdgcn_global_load_lds((const __attribute__((address_space(1))) void*)ga, \
                                       (__attribute__((address_space(3))) void*)la, 16, 0, 0); \
      __builtin_amdgcn_global_load_lds((const __attribute__((address_space(1))) void*)gb, \
                                       (__attribute__((address_space(3))) void*)lb, 16, 0, 0); \
    }                                                                         \
  } while (0)

  ISSUE(0, 0);

  for (int kc = 0; kc < Dd / 32; ++kc) {
    __syncthreads();      // drains vmem -> tile kc ready; syncs buffer reuse
    if (kc + 1 < Dd / 32) ISSUE(kc + 1, (kc + 1) & 1);   // lands next barrier
    const unsigned short* Ab = &As[kc & 1][0];
    const unsigned short* Bb = &Bs[kc & 1][0];
    const int ra = l & 15;
    const int kb = (l >> 4) * 8;               // 4 chunks spread across lanes
    bf16x8 af[4], bfr[4];
#pragma unroll
    for (int m = 0; m < 4; ++m)
      af[m] = *(const bf16x8*)&Ab[(wr * 64 + m * 16 + ra) * 32 + kb];
#pragma unroll
    for (int n = 0; n < 4; ++n)
      bfr[n] = *(const bf16x8*)&Bb[(wc * 64 + n * 16 + ra) * 32 + kb];
#pragma unroll
    for (int m = 0; m < 4; ++m)
#pragma unroll
      for (int n = 0; n < 4; ++n)
        acc[m][n] = __builtin_amdgcn_mfma_f32_16x16x32_bf16(af[m], bfr[n], acc[m][n], 0, 0, 0);
  }
#undef ISSUE

  // ------- fused per-half top-3 epilogue -------
  const int base4 = wr * 64 + (l >> 4) * 4;      // lane's local code base
  float4 cs[4];
#pragma unroll
  for (int m = 0; m < 4; ++m)
    cs[m] = *(const float4*)&csq[cm * 128 + base4 + m * 16];

  const int slot = cm * 2 + wr;                  // 0..15
  const int tok0 = tn * 128 + wc * 64 + (l & 15);

#pragma unroll
  for (int n = 0; n < 4; ++n) {
    float v0 = 3.4e38f, v1 = 3.4e38f, v2 = 3.4e38f;
    int i0 = 0x7fffffff, i1 = 0x7fffffff;
#pragma unroll
    for (int m = 0; m < 4; ++m) {
#pragma unroll
      for (int r = 0; r < 4; ++r) {
        float sv = fmaf(-2.0f, acc[m][n][r], ((const float*)&cs[m])[r]);
        int idx = cm * 128 + base4 + m * 16 + r;
        if (sv < v0)      { v2 = v1; v1 = v0; i1 = i0; v0 = sv; i0 = idx; }
        else if (sv < v1) { v2 = v1; v1 = sv; i1 = idx; }
        else if (sv < v2) { v2 = sv; }
      }
    }
#pragma unroll
    for (int o = 16; o <= 32; o <<= 1) {
      float w0 = __shfl_xor(v0, o), w1 = __shfl_xor(v1, o), w2 = __shfl_xor(v2, o);
      int  j0 = __shfl_xor(i0, o), j1 = __shfl_xor(i1, o);
      bool f = (w0 < v0) || (w0 == v0 && j0 < i0);
      float A0 = f ? w0 : v0, A1 = f ? w1 : v1, A2 = f ? w2 : v2;
      int  Ai0 = f ? j0 : i0, Ai1 = f ? j1 : i1;
      float B0 = f ? v0 : w0, B1 = f ? v1 : w1;
      int  Bi0 = f ? i0 : j0;
      bool g = (A1 < B0) || (A1 == B0 && Ai1 < Bi0);
      v0 = A0; i0 = Ai0;
      v1 = g ? A1 : B0; i1 = g ? Ai1 : Bi0;
      v2 = g ? fminf(A2, B0) : fminf(A1, B1);
    }
    if ((l >> 4) == 0)
      part[(size_t)slot * Ttok + tok0 + n * 16] = make_float4(
          v0, v1, __uint_as_float((unsigned)i0 | ((unsigned)i1 << 16)), v2);
  }
}

// exact fp32 rescore of one code (wave-cooperative), uniform n
__device__ inline void rescore(int n, const float4& xa, const float4& xb,
                               const float* __restrict__ cb,
                               const float* __restrict__ csq, int l,
                               float& bestv, int& besti) {
  const float4* cr = (const float4*)(cb + (size_t)n * Dd);
  float4 ca = cr[l * 2], cc = cr[l * 2 + 1];
  float p = xa.x*ca.x + xa.y*ca.y + xa.z*ca.z + xa.w*ca.w
          + xb.x*cc.x + xb.y*cc.y + xb.z*cc.z + xb.w*cc.w;
#pragma unroll
  for (int o = 32; o; o >>= 1) p += __shfl_xor(p, o);
  float sc = csq[n] - 2.0f * p;
  if (sc < bestv || (sc == bestv && n < besti)) { bestv = sc; besti = n; }
}

// exact rescore of a full 64-code half: one code per lane, then wave-argmin
__device__ inline void rescore_half(int h, const float* __restrict__ xrow,
                                    const float* __restrict__ cb,
                                    const float* __restrict__ csq, int l,
                                    float& bestv, int& besti) {
  int n = h * 64 + l;
  const float4* cr = (const float4*)(cb + (size_t)n * Dd);
  const float4* xr = (const float4*)xrow;
  float p = 0.f;
#pragma unroll 8
  for (int j = 0; j < 128; ++j) {
    float4 c4 = cr[j], x4 = xr[j];
    p += c4.x*x4.x + c4.y*x4.y + c4.z*x4.z + c4.w*x4.w;
  }
  float sc = csq[n] - 2.0f * p;
#pragma unroll
  for (int o = 1; o < 64; o <<= 1) {
    float ov = __shfl_xor(sc, o); int oi = __shfl_xor(n, o);
    if (ov < sc || (ov == sc && oi < n)) { sc = ov; n = oi; }
  }
  if (sc < bestv || (sc == bestv && n < besti)) { bestv = sc; besti = n; }
}

// ---- per-token: merge 16 half partials; fast path when exact coarse
// runner-up trails min by > GAP (no loads); else rescore candidates.
// NOTE (r14/r15 lesson): hist atomic stays fire-and-forget — NO barrier
// or waitcnt after any contended atomic.
__global__ __launch_bounds__(256) void k_select(
    const float4* __restrict__ part, const float* __restrict__ x,
    const float* __restrict__ cb, const float* __restrict__ csq,
    int* __restrict__ idxb, float* __restrict__ idxf, float* __restrict__ hist) {
  const int tid = threadIdx.x, wid = tid >> 6, l = tid & 63;
  const int t = blockIdx.x * 4 + wid;
  float v0 = 3.4e38f, v1 = 3.4e38f, v2 = 3.4e38f;
  int i0 = 0x7fffffff, i1 = 0x7fffffff;
  if (l < 16) {
    float4 e = part[(size_t)l * Ttok + t];
    v0 = e.x; v1 = e.y; v2 = e.w;
    unsigned ii = __float_as_uint(e.z);
    i0 = (int)(ii & 0xffff); i1 = (int)(ii >> 16);
  }
  float A0 = v0, A1 = v1; int Ai0 = i0, Ai1 = i1;
#pragma unroll
  for (int o = 1; o < 16; o <<= 1) {
    float w0 = __shfl_xor(A0, o), w1 = __shfl_xor(A1, o);
    int  j0 = __shfl_xor(Ai0, o), j1 = __shfl_xor(Ai1, o);
    bool f = (w0 < A0) || (w0 == A0 && j0 < Ai0);
    float B0 = f ? A0 : w0; int Bi0 = f ? Ai0 : j0;
    float W1 = f ? w1 : A1; int Wi1 = f ? j1 : Ai1;
    if (f) { A0 = w0; Ai0 = j0; }
    bool g = (B0 < W1) || (B0 == W1 && Bi0 < Wi1);
    A1 = g ? B0 : W1; Ai1 = g ? Bi0 : Wi1;
  }
  const float m  = __shfl(A0, 0);
  const float g1 = __shfl(A1, 0);
  const int   gi = __shfl(Ai0, 0);
  int besti;
  if (g1 - m > GAP) {
    besti = gi;
  } else {
    const float thr = m + GAP;
    const float* xrow = x + (size_t)t * Dd;
    const float4* xr = (const float4*)xrow;
    float4 xa = xr[l * 2], xb = xr[l * 2 + 1];
    float bestv = 3.4e38f; besti = 0x7fffffff;
    for (int h = 0; h < 16; ++h) {
      float b0 = __shfl(v0, h);
      if (b0 > thr) continue;
      float b1 = __shfl(v1, h), b2 = __shfl(v2, h);
      int bi0 = __shfl(i0, h), bi1 = __shfl(i1, h);
      if (b2 <= thr) {
        rescore_half(h, xrow, cb, csq, l, bestv, besti);
      } else {
        rescore(bi0, xa, xb, cb, csq, l, bestv, besti);
        if (b1 <= thr) rescore(bi1, xa, xb, cb, csq, l, bestv, besti);
      }
    }
  }
  if (l == 0) {
    idxb[t] = besti;
    idxf[t] = (float)besti;
    atomicAdd(&hist[besti], 1.0f);
  }
}

// ----------------- prefix sum of histogram (1 block, 256 thr, wave scan)
__global__ __launch_bounds__(256) void k_offsets(const float* __restrict__ hist,
                                                 int* __restrict__ cursor) {
  __shared__ int wsum[4];
  const int tid = threadIdx.x, l = tid & 63, wd = tid >> 6;
  const int base = tid * 4;
  int c0 = (int)hist[base], c1 = (int)hist[base + 1],
      c2 = (int)hist[base + 2], c3 = (int)hist[base + 3];
  int sum = c0 + c1 + c2 + c3;
  int sc = sum;
#pragma unroll
  for (int o = 1; o < 64; o <<= 1) { int v = __shfl_up(sc, o); if (l >= o) sc += v; }
  if (l == 63) wsum[wd] = sc;
  __syncthreads();
  int wbase = 0;
  for (int i = 0; i < wd; ++i) wbase += wsum[i];
  int e = wbase + sc - sum;
  cursor[base]     = e;
  cursor[base + 1] = e + c0;
  cursor[base + 2] = e + c0 + c1;
  cursor[base + 3] = e + c0 + c1 + c2;
}

// -------------------------------- bucket tokens by index (code-sorted order)
__global__ __launch_bounds__(256) void k_scatter(const int* __restrict__ idxb,
                                                 int* __restrict__ cursor,
                                                 int* __restrict__ bucket,
                                                 int* __restrict__ bcode) {
  int t = blockIdx.x * 256 + threadIdx.x;
  if (t < Ttok) {
    int n = idxb[t];
    int p = atomicAdd(&cursor[n], 1);
    bucket[p] = t;
    bcode[p] = n;
  }
}

// ------- load-balanced segmented sum: dw[n][d] += x rows of chunk segments
__global__ __launch_bounds__(512) void k_dw_part(
    const float* __restrict__ x, const int* __restrict__ bucket,
    const int* __restrict__ bcode, float* __restrict__ dw) {
  __shared__ int sh_t[CH], sh_n[CH];
  const int tid = threadIdx.x;
  const int p0 = blockIdx.x * CH;
  if (tid < CH) { sh_t[tid] = bucket[p0 + tid]; sh_n[tid] = bcode[p0 + tid]; }
  __syncthreads();
  float v[CH];
#pragma unroll
  for (int j = 0; j < CH; ++j)
    v[j] = x[(size_t)sh_t[j] * Dd + tid];
  float acc = v[0]; int cur = sh_n[0];
#pragma unroll
  for (int j = 1; j < CH; ++j) {
    int n = sh_n[j];
    if (n != cur) { atomicAdd(&dw[(size_t)cur * Dd + tid], acc); acc = 0.f; cur = n; }
    acc += v[j];
  }
  atomicAdd(&dw[(size_t)cur * Dd + tid], acc);
}

// ------- per-code loss terms: sxqp[n] = q_n . dw_n ; sqqp[n] = hist_n |q_n|^2
// Plain per-code stores (no atomics).
__global__ __launch_bounds__(128) void k_lossterms(
    const float* __restrict__ ema, const float* __restrict__ dw,
    const float* __restrict__ counts, const float* __restrict__ hist,
    float* __restrict__ sxqp, float* __restrict__ sqqp) {
  const int n = blockIdx.x, tid = threadIdx.x;
  const float hc = hist[n];
  const float inv = 1.0f / (DECAYc * counts[n] + (1.0f - DECAYc) * hc);
  f32x4 e = ((const f32x4*)(ema + (size_t)n * Dd))[tid];
  f32x4 d = ((const f32x4*)(dw  + (size_t)n * Dd))[tid];
  f32x4 q = (DECAYc * e + (1.0f - DECAYc) * d) * inv;
  float xq = q[0]*d[0] + q[1]*d[1] + q[2]*d[2] + q[3]*d[3];
  float qq = q[0]*q[0] + q[1]*q[1] + q[2]*q[2] + q[3]*q[3];
#pragma unroll
  for (int o = 32; o; o >>= 1) { xq += __shfl_down(xq, o); qq += __shfl_down(qq, o); }
  __shared__ float sx[2], sq[2];
  const int wd = tid >> 6, l = tid & 63;
  if (l == 0) { sx[wd] = xq; sq[wd] = qq; }
  __syncthreads();
  if (tid == 0) { sxqp[n] = sx[0] + sx[1]; sqqp[n] = hc * (sq[0] + sq[1]); }
}

// ------- quantized = (decay*ema[idx] + (1-decay)*dw[idx]) / cnt[idx]
// Pure gather + stream write: NO x read, NO reduction (loss via identity).
__global__ __launch_bounds__(256) void quant_out(
    const float* __restrict__ ema, const float* __restrict__ dw,
    const float* __restrict__ counts, const float* __restrict__ hist,
    const int* __restrict__ idx, float* __restrict__ out_q) {
  const int e0 = blockIdx.x * 256 + threadIdx.x;
  const int gsz = 524288;                    // 2048 blocks * 256 threads
  int n[4];
#pragma unroll
  for (int j = 0; j < 4; ++j) n[j] = idx[(e0 + j * gsz) >> 7];
  float inv[4];
#pragma unroll
  for (int j = 0; j < 4; ++j)
    inv[j] = 1.0f / (DECAYc * counts[n[j]] + (1.0f - DECAYc) * hist[n[j]]);
  f32x4 e4[4], d4[4];
#pragma unroll
  for (int j = 0; j < 4; ++j) {
    const int e = e0 + j * gsz;
    e4[j] = ((const f32x4*)(ema + (size_t)n[j] * Dd))[e & 127];
    d4[j] = ((const f32x4*)(dw  + (size_t)n[j] * Dd))[e & 127];
  }
#pragma unroll
  for (int j = 0; j < 4; ++j) {
    f32x4 q = (DECAYc * e4[j] + (1.0f - DECAYc) * d4[j]) * inv[j];
    __builtin_nontemporal_store(q, &((f32x4*)out_q)[e0 + j * gsz]);
  }
}

// loss = 0.5/(T*D) * (Sxx - 2*Sxq + Sqq), partials reduced in DOUBLE
// (the three sums are ~8.4M each; fp32 cancellation would cost ~1e-5 rel).
__global__ __launch_bounds__(256) void loss_final(
    const float* __restrict__ sxxp, const float* __restrict__ sxqp,
    const float* __restrict__ sqqp, float* __restrict__ out_loss) {
  const int tid = threadIdx.x;
  double acc = 0.0;
  for (int i = tid; i < 8192; i += 256) acc += (double)sxxp[i];
  for (int i = tid; i < 1024; i += 256) acc -= 2.0 * (double)sxqp[i];
  for (int i = tid; i < 1024; i += 256) acc += (double)sqqp[i];
#pragma unroll
  for (int o = 32; o; o >>= 1) acc += __shfl_down(acc, o);
  __shared__ double red[4];
  const int wd = tid >> 6, l = tid & 63;
  if (l == 0) red[wd] = acc;
  __syncthreads();
  if (tid == 0)
    *out_loss = (float)((red[0] + red[1] + red[2] + red[3]) *
                        (0.5 / ((double)Ttok * (double)Dd)));
}

// ---------------------------------------------------------------- launch
extern "C" void kernel_launch(void* const* d_in, const int* in_sizes, int n_in,
                              void* d_out, int out_size, void* d_ws, size_t ws_size,
                              hipStream_t stream) {
  const float* x      = (const float*)d_in[0];
  const float* cb     = (const float*)d_in[1];
  const float* ema    = (const float*)d_in[2];
  const float* counts = (const float*)d_in[3];

  float* out      = (float*)d_out;
  float* q_out    = out;
  float* loss_out = out + (size_t)Ttok * Dd;
  float* idxf_out = loss_out + 1;
  // d_out head reuse before quant_out overwrites it:
  //   part: float4[16][16384] = 4 MB at q_out[0 .. 1M floats)
  //   xh:   bf16 x (16.8 MB)   at q_out[2M .. 6.2M floats)   (no overlap)
  float4* part = (float4*)q_out;
  unsigned short* xh = (unsigned short*)(q_out + 2097152);

  // workspace layout (float offsets)
  float* ws = (float*)d_ws;
  unsigned short* cbh = (unsigned short*)ws;           // [0, 262144)  bf16 cb
  float* dw      = ws + 262144;                        // 524288 (zeroed in k_prep)
  float* hist    = ws + 786432;                        // 1024   (zeroed in k_prep)
  float* csq     = ws + 787460;                        // 1024
  int*   cursor  = (int*)(ws + 789508);                // 1024
  int*   bucket  = (int*)(ws + 790532);                // 16384
  int*   bcode   = (int*)(ws + 806916);                // 16384
  int*   idxb    = (int*)(ws + 823300);                // 16384
  float* sxxp    = ws + 839684;                        // 8192 (all slots written)
  float* sxqp    = ws + 847876;                        // 1024 (all slots written)
  float* sqqp    = ws + 848900;                        // 1024 (all slots written)

  k_prep<<<NB_CB + NB_Z + NB_X, 256, 0, stream>>>(cb, x, cbh, csq, xh,
                                                  (float4*)dw, sxxp);
  k_gemm_scores<<<(Nn / 128) * (Ttok / 128), 256, 0, stream>>>(cbh, xh, csq, part);
  k_select<<<Ttok / 4, 256, 0, stream>>>(part, x, cb, csq, idxb, idxf_out, hist);
  k_offsets<<<1, 256, 0, stream>>>(hist, cursor);
  k_scatter<<<Ttok / 256, 256, 0, stream>>>(idxb, cursor, bucket, bcode);
  k_dw_part<<<Ttok / CH, 512, 0, stream>>>(x, bucket, bcode, dw);
  k_lossterms<<<Nn, 128, 0, stream>>>(ema, dw, counts, hist, sxqp, sqqp);
  quant_out<<<2048, 256, 0, stream>>>(ema, dw, counts, hist, idxb, q_out);
  loss_final<<<1, 256, 0, stream>>>(sxxp, sxqp, sqqp, loss_out);
}

// Round 18
// 114.090 us; speedup vs baseline: 2.0396x; 1.0339x over previous
//
#include <hip/hip_runtime.h>
#include <hip/hip_bf16.h>

constexpr int Dd   = 512;
constexpr int Nn   = 1024;
constexpr int Ttok = 16384;              // B*L
constexpr float DECAYc = 0.99f;
// Coarse scores are f32 MFMA of bf16-rounded inputs: error std ~0.07.
// GAP=3.0 on the EXACT coarse runner-up (top-3 store makes g1 exact).
constexpr float GAP = 3.0f;
constexpr int CH = 16;                   // tokens per dw chunk

typedef short bf16x8 __attribute__((ext_vector_type(8)));
typedef float f32x4  __attribute__((ext_vector_type(4)));

__device__ inline unsigned cvtpk(float lo, float hi) { // 2xf32 -> packed bf16
  unsigned r;
  asm("v_cvt_pk_bf16_f32 %0, %1, %2" : "=v"(r) : "v"(lo), "v"(hi));
  return r;
}

// ---- fused prep: cb->bf16 + csq (blocks 0..255), zero dw/hist
// (blocks 256..287), x->bf16 + per-wave Sxx partials (blocks 288..2335).
// NO contended atomics (r16 lesson); per-wave partials to own slots.
constexpr int NB_CB = 256, NB_Z = 32, NB_X = 2048;
constexpr int ZF4 = 131328;              // float4s to zero (dw+hist)
__global__ __launch_bounds__(256) void k_prep(
    const float* __restrict__ cb, const float* __restrict__ x,
    unsigned short* __restrict__ cbh, float* __restrict__ csq,
    unsigned short* __restrict__ xh, float4* __restrict__ zbase,
    float* __restrict__ sxxp) {
  const int b = blockIdx.x, tid = threadIdx.x;
  if (b < NB_CB) {
    const int n = b * 4 + (tid >> 6), l = tid & 63;
    const float4* r = (const float4*)(cb + (size_t)n * Dd);
    float4 a = r[l], c = r[l + 64];
    float ss = a.x*a.x + a.y*a.y + a.z*a.z + a.w*a.w
             + c.x*c.x + c.y*c.y + c.z*c.z + c.w*c.w;
    uint2 ua, uc;
    ua.x = cvtpk(a.x, a.y); ua.y = cvtpk(a.z, a.w);
    uc.x = cvtpk(c.x, c.y); uc.y = cvtpk(c.z, c.w);
    ((uint2*)(cbh + (size_t)n * Dd))[l]      = ua;
    ((uint2*)(cbh + (size_t)n * Dd))[l + 64] = uc;
#pragma unroll
    for (int o = 32; o; o >>= 1) ss += __shfl_down(ss, o);
    if (l == 0) csq[n] = ss;
  } else if (b < NB_CB + NB_Z) {
    const float4 z = make_float4(0.f, 0.f, 0.f, 0.f);
    for (int i = (b - NB_CB) * 256 + tid; i < ZF4; i += NB_Z * 256)
      zbase[i] = z;
  } else {
    const int bx = b - (NB_CB + NB_Z);
    float sx = 0.f;
#pragma unroll
    for (int k = 0; k < 2; ++k) {
      const int i = bx * 512 + k * 256 + tid;     // 8-float chunk id
      float4 a = ((const float4*)x)[i * 2];
      float4 c = ((const float4*)x)[i * 2 + 1];
      sx += a.x*a.x + a.y*a.y + a.z*a.z + a.w*a.w
          + c.x*c.x + c.y*c.y + c.z*c.z + c.w*c.w;
      uint4 o;
      o.x = cvtpk(a.x, a.y); o.y = cvtpk(a.z, a.w);
      o.z = cvtpk(c.x, c.y); o.w = cvtpk(c.z, c.w);
      ((uint4*)xh)[i] = o;
    }
#pragma unroll
    for (int o = 32; o; o >>= 1) sx += __shfl_down(sx, o);
    if ((tid & 63) == 0) sxxp[bx * 4 + (tid >> 6)] = sx;   // own slot, no atomic
  }
}

// ------------- MFMA GEMM, BK=32, 3-buffer 2-deep pipeline (T3/T4-lite):
// raw s_barrier + counted vmcnt(4) (never 0 in-loop) so each tile's
// global_load_lds gets TWO MFMA phases to land instead of one.
// 48 KB LDS -> 3 blocks/CU. 64B rows = conflict-free reads, linear dest.
// vmcnt ledger: prologue issues tiles 0,1 (4 ops each/thread); iter kc
// waits vmcnt(4) [tile kc landed, kc+1 in flight], issues kc+2; last
// iter waits vmcnt(0). Buffer kc%3 overwrite is safe: its readers (tile
// kc-1, read in iter kc-1) finished before barrier(kc).
// Fused per-64-code-half top-3 argmin epilogue (v0,v1,i0|i1,v2).
__global__ __launch_bounds__(256) void k_gemm_scores(
    const unsigned short* __restrict__ cbh, const unsigned short* __restrict__ xh,
    const float* __restrict__ csq, float4* __restrict__ part) {
  __shared__ unsigned short As[3][128 * 32];   // codes  (8 KB x3)
  __shared__ unsigned short Bs[3][128 * 32];   // tokens (8 KB x3)
  const int tid = threadIdx.x;
  const int w = tid >> 6, l = tid & 63;
  const int b = blockIdx.x;
  const int s = (b & 7) * 128 + (b >> 3);      // XCD-aware bijective swizzle
  const int cm = s & 7;        // code-block  (M)
  const int tn = s >> 3;       // token-block (N)
  const int wr = w >> 1, wc = w & 1;

  const int srow = tid >> 2;                   // 0..63 staging row
  const int scol = (tid & 3) * 8;              // elem offset of 16B chunk

  f32x4 acc[4][4] = {};

  const unsigned short* gA0 = cbh + (size_t)(cm * 128) * Dd;
  const unsigned short* gB0 = xh  + (size_t)(tn * 128) * Dd;

#define ISSUE(KC, BUF) do {                                                   \
    const int k0_ = (KC) * 32;                                                \
    _Pragma("unroll")                                                         \
    for (int p = 0; p < 2; ++p) {                                             \
      const unsigned short* ga = gA0 + (size_t)(p * 64 + srow) * Dd + k0_ + scol; \
      const unsigned short* gb = gB0 + (size_t)(p * 64 + srow) * Dd + k0_ + scol; \
      char* la = (char*)&As[BUF][0] + p * 4096 + w * 1024;                    \
      char* lb = (char*)&Bs[BUF][0] + p * 4096 + w * 1024;                    \
      __builtin_amdgcn_global_load_lds((const __attribute__((address_space(1))) void*)ga, \
                                       (__attribute__((address_space(3))) void*)la, 16, 0, 0); \
      __builtin_amdgcn_global_load_lds((const __attribute__((address_space(1))) void*)gb, \
                                       (__attribute__((address_space(3))) void*)lb, 16, 0, 0); \
    }                                                                         \
  } while (0)

  ISSUE(0, 0);
  ISSUE(1, 1);

#pragma unroll
  for (int kc = 0; kc < Dd / 32; ++kc) {
    if (kc < Dd / 32 - 1)
      asm volatile("s_waitcnt vmcnt(4)\n\ts_barrier" ::: "memory");
    else
      asm volatile("s_waitcnt vmcnt(0)\n\ts_barrier" ::: "memory");
    __builtin_amdgcn_sched_barrier(0);
    if (kc + 2 < Dd / 32) ISSUE(kc + 2, (kc + 2) % 3);
    const unsigned short* Ab = &As[kc % 3][0];
    const unsigned short* Bb = &Bs[kc % 3][0];
    const int ra = l & 15;
    const int kb = (l >> 4) * 8;               // 4 chunks spread across lanes
    bf16x8 af[4], bfr[4];
#pragma unroll
    for (int m = 0; m < 4; ++m)
      af[m] = *(const bf16x8*)&Ab[(wr * 64 + m * 16 + ra) * 32 + kb];
#pragma unroll
    for (int n = 0; n < 4; ++n)
      bfr[n] = *(const bf16x8*)&Bb[(wc * 64 + n * 16 + ra) * 32 + kb];
#pragma unroll
    for (int m = 0; m < 4; ++m)
#pragma unroll
      for (int n = 0; n < 4; ++n)
        acc[m][n] = __builtin_amdgcn_mfma_f32_16x16x32_bf16(af[m], bfr[n], acc[m][n], 0, 0, 0);
  }
#undef ISSUE

  // ------- fused per-half top-3 epilogue -------
  const int base4 = wr * 64 + (l >> 4) * 4;      // lane's local code base
  float4 cs[4];
#pragma unroll
  for (int m = 0; m < 4; ++m)
    cs[m] = *(const float4*)&csq[cm * 128 + base4 + m * 16];

  const int slot = cm * 2 + wr;                  // 0..15
  const int tok0 = tn * 128 + wc * 64 + (l & 15);

#pragma unroll
  for (int n = 0; n < 4; ++n) {
    float v0 = 3.4e38f, v1 = 3.4e38f, v2 = 3.4e38f;
    int i0 = 0x7fffffff, i1 = 0x7fffffff;
#pragma unroll
    for (int m = 0; m < 4; ++m) {
#pragma unroll
      for (int r = 0; r < 4; ++r) {
        float sv = fmaf(-2.0f, acc[m][n][r], ((const float*)&cs[m])[r]);
        int idx = cm * 128 + base4 + m * 16 + r;
        if (sv < v0)      { v2 = v1; v1 = v0; i1 = i0; v0 = sv; i0 = idx; }
        else if (sv < v1) { v2 = v1; v1 = sv; i1 = idx; }
        else if (sv < v2) { v2 = sv; }
      }
    }
#pragma unroll
    for (int o = 16; o <= 32; o <<= 1) {
      float w0 = __shfl_xor(v0, o), w1 = __shfl_xor(v1, o), w2 = __shfl_xor(v2, o);
      int  j0 = __shfl_xor(i0, o), j1 = __shfl_xor(i1, o);
      bool f = (w0 < v0) || (w0 == v0 && j0 < i0);
      float A0 = f ? w0 : v0, A1 = f ? w1 : v1, A2 = f ? w2 : v2;
      int  Ai0 = f ? j0 : i0, Ai1 = f ? j1 : i1;
      float B0 = f ? v0 : w0, B1 = f ? v1 : w1;
      int  Bi0 = f ? i0 : j0;
      bool g = (A1 < B0) || (A1 == B0 && Ai1 < Bi0);
      v0 = A0; i0 = Ai0;
      v1 = g ? A1 : B0; i1 = g ? Ai1 : Bi0;
      v2 = g ? fminf(A2, B0) : fminf(A1, B1);
    }
    if ((l >> 4) == 0)
      part[(size_t)slot * Ttok + tok0 + n * 16] = make_float4(
          v0, v1, __uint_as_float((unsigned)i0 | ((unsigned)i1 << 16)), v2);
  }
}

// exact fp32 rescore of one code (wave-cooperative), uniform n
__device__ inline void rescore(int n, const float4& xa, const float4& xb,
                               const float* __restrict__ cb,
                               const float* __restrict__ csq, int l,
                               float& bestv, int& besti) {
  const float4* cr = (const float4*)(cb + (size_t)n * Dd);
  float4 ca = cr[l * 2], cc = cr[l * 2 + 1];
  float p = xa.x*ca.x + xa.y*ca.y + xa.z*ca.z + xa.w*ca.w
          + xb.x*cc.x + xb.y*cc.y + xb.z*cc.z + xb.w*cc.w;
#pragma unroll
  for (int o = 32; o; o >>= 1) p += __shfl_xor(p, o);
  float sc = csq[n] - 2.0f * p;
  if (sc < bestv || (sc == bestv && n < besti)) { bestv = sc; besti = n; }
}

// exact rescore of a full 64-code half: one code per lane, then wave-argmin
__device__ inline void rescore_half(int h, const float* __restrict__ xrow,
                                    const float* __restrict__ cb,
                                    const float* __restrict__ csq, int l,
                                    float& bestv, int& besti) {
  int n = h * 64 + l;
  const float4* cr = (const float4*)(cb + (size_t)n * Dd);
  const float4* xr = (const float4*)xrow;
  float p = 0.f;
#pragma unroll 8
  for (int j = 0; j < 128; ++j) {
    float4 c4 = cr[j], x4 = xr[j];
    p += c4.x*x4.x + c4.y*x4.y + c4.z*x4.z + c4.w*x4.w;
  }
  float sc = csq[n] - 2.0f * p;
#pragma unroll
  for (int o = 1; o < 64; o <<= 1) {
    float ov = __shfl_xor(sc, o); int oi = __shfl_xor(n, o);
    if (ov < sc || (ov == sc && oi < n)) { sc = ov; n = oi; }
  }
  if (sc < bestv || (sc == bestv && n < besti)) { bestv = sc; besti = n; }
}

// ---- per-token: merge 16 half partials; fast path when exact coarse
// runner-up trails min by > GAP (no loads); else rescore candidates.
// NOTE (r14/r15 lesson): hist atomic stays fire-and-forget — NO barrier
// or waitcnt after any contended atomic.
__global__ __launch_bounds__(256) void k_select(
    const float4* __restrict__ part, const float* __restrict__ x,
    const float* __restrict__ cb, const float* __restrict__ csq,
    int* __restrict__ idxb, float* __restrict__ idxf, float* __restrict__ hist) {
  const int tid = threadIdx.x, wid = tid >> 6, l = tid & 63;
  const int t = blockIdx.x * 4 + wid;
  float v0 = 3.4e38f, v1 = 3.4e38f, v2 = 3.4e38f;
  int i0 = 0x7fffffff, i1 = 0x7fffffff;
  if (l < 16) {
    float4 e = part[(size_t)l * Ttok + t];
    v0 = e.x; v1 = e.y; v2 = e.w;
    unsigned ii = __float_as_uint(e.z);
    i0 = (int)(ii & 0xffff); i1 = (int)(ii >> 16);
  }
  float A0 = v0, A1 = v1; int Ai0 = i0, Ai1 = i1;
#pragma unroll
  for (int o = 1; o < 16; o <<= 1) {
    float w0 = __shfl_xor(A0, o), w1 = __shfl_xor(A1, o);
    int  j0 = __shfl_xor(Ai0, o), j1 = __shfl_xor(Ai1, o);
    bool f = (w0 < A0) || (w0 == A0 && j0 < Ai0);
    float B0 = f ? A0 : w0; int Bi0 = f ? Ai0 : j0;
    float W1 = f ? w1 : A1; int Wi1 = f ? j1 : Ai1;
    if (f) { A0 = w0; Ai0 = j0; }
    bool g = (B0 < W1) || (B0 == W1 && Bi0 < Wi1);
    A1 = g ? B0 : W1; Ai1 = g ? Bi0 : Wi1;
  }
  const float m  = __shfl(A0, 0);
  const float g1 = __shfl(A1, 0);
  const int   gi = __shfl(Ai0, 0);
  int besti;
  if (g1 - m > GAP) {
    besti = gi;
  } else {
    const float thr = m + GAP;
    const float* xrow = x + (size_t)t * Dd;
    const float4* xr = (const float4*)xrow;
    float4 xa = xr[l * 2], xb = xr[l * 2 + 1];
    float bestv = 3.4e38f; besti = 0x7fffffff;
    for (int h = 0; h < 16; ++h) {
      float b0 = __shfl(v0, h);
      if (b0 > thr) continue;
      float b1 = __shfl(v1, h), b2 = __shfl(v2, h);
      int bi0 = __shfl(i0, h), bi1 = __shfl(i1, h);
      if (b2 <= thr) {
        rescore_half(h, xrow, cb, csq, l, bestv, besti);
      } else {
        rescore(bi0, xa, xb, cb, csq, l, bestv, besti);
        if (b1 <= thr) rescore(bi1, xa, xb, cb, csq, l, bestv, besti);
      }
    }
  }
  if (l == 0) {
    idxb[t] = besti;
    idxf[t] = (float)besti;
    atomicAdd(&hist[besti], 1.0f);
  }
}

// ----------------- prefix sum of histogram (1 block, 256 thr, wave scan)
__global__ __launch_bounds__(256) void k_offsets(const float* __restrict__ hist,
                                                 int* __restrict__ cursor) {
  __shared__ int wsum[4];
  const int tid = threadIdx.x, l = tid & 63, wd = tid >> 6;
  const int base = tid * 4;
  int c0 = (int)hist[base], c1 = (int)hist[base + 1],
      c2 = (int)hist[base + 2], c3 = (int)hist[base + 3];
  int sum = c0 + c1 + c2 + c3;
  int sc = sum;
#pragma unroll
  for (int o = 1; o < 64; o <<= 1) { int v = __shfl_up(sc, o); if (l >= o) sc += v; }
  if (l == 63) wsum[wd] = sc;
  __syncthreads();
  int wbase = 0;
  for (int i = 0; i < wd; ++i) wbase += wsum[i];
  int e = wbase + sc - sum;
  cursor[base]     = e;
  cursor[base + 1] = e + c0;
  cursor[base + 2] = e + c0 + c1;
  cursor[base + 3] = e + c0 + c1 + c2;
}

// -------------------------------- bucket tokens by index (code-sorted order)
__global__ __launch_bounds__(256) void k_scatter(const int* __restrict__ idxb,
                                                 int* __restrict__ cursor,
                                                 int* __restrict__ bucket,
                                                 int* __restrict__ bcode) {
  int t = blockIdx.x * 256 + threadIdx.x;
  if (t < Ttok) {
    int n = idxb[t];
    int p = atomicAdd(&cursor[n], 1);
    bucket[p] = t;
    bcode[p] = n;
  }
}

// ------- load-balanced segmented sum: dw[n][d] += x rows of chunk segments
__global__ __launch_bounds__(512) void k_dw_part(
    const float* __restrict__ x, const int* __restrict__ bucket,
    const int* __restrict__ bcode, float* __restrict__ dw) {
  __shared__ int sh_t[CH], sh_n[CH];
  const int tid = threadIdx.x;
  const int p0 = blockIdx.x * CH;
  if (tid < CH) { sh_t[tid] = bucket[p0 + tid]; sh_n[tid] = bcode[p0 + tid]; }
  __syncthreads();
  float v[CH];
#pragma unroll
  for (int j = 0; j < CH; ++j)
    v[j] = x[(size_t)sh_t[j] * Dd + tid];
  float acc = v[0]; int cur = sh_n[0];
#pragma unroll
  for (int j = 1; j < CH; ++j) {
    int n = sh_n[j];
    if (n != cur) { atomicAdd(&dw[(size_t)cur * Dd + tid], acc); acc = 0.f; cur = n; }
    acc += v[j];
  }
  atomicAdd(&dw[(size_t)cur * Dd + tid], acc);
}

// ------- quantized gather + per-code loss terms MERGED in one launch.
// Blocks [0,2048): quantized = (decay*ema[idx]+(1-decay)*dw[idx])/cnt[idx]
// (pure gather + NT stream write, no x read). Blocks [2048,3072): per-code
// sxqp/sqqp partials (plain stores, no atomics). Independent outputs,
// identical dependencies (dw+hist complete) -> safe co-launch.
__global__ __launch_bounds__(256) void quant_out(
    const float* __restrict__ ema, const float* __restrict__ dw,
    const float* __restrict__ counts, const float* __restrict__ hist,
    const int* __restrict__ idx, float* __restrict__ out_q,
    float* __restrict__ sxqp, float* __restrict__ sqqp) {
  const int b = blockIdx.x, tid = threadIdx.x;
  if (b >= 2048) {                       // ---- loss-terms blocks ----
    const int n = b - 2048;
    if (tid < 128) {
      const float hc = hist[n];
      const float inv = 1.0f / (DECAYc * counts[n] + (1.0f - DECAYc) * hc);
      f32x4 e = ((const f32x4*)(ema + (size_t)n * Dd))[tid];
      f32x4 d = ((const f32x4*)(dw  + (size_t)n * Dd))[tid];
      f32x4 q = (DECAYc * e + (1.0f - DECAYc) * d) * inv;
      float xq = q[0]*d[0] + q[1]*d[1] + q[2]*d[2] + q[3]*d[3];
      float qq = q[0]*q[0] + q[1]*q[1] + q[2]*q[2] + q[3]*q[3];
#pragma unroll
      for (int o = 32; o; o >>= 1) { xq += __shfl_down(xq, o); qq += __shfl_down(qq, o); }
      __shared__ float sx[2], sq[2];
      const int wd = tid >> 6, l = tid & 63;
      if (l == 0) { sx[wd] = xq; sq[wd] = qq; }
      __syncthreads();
      if (tid == 0) { sxqp[n] = sx[0] + sx[1]; sqqp[n] = hc * (sq[0] + sq[1]); }
    }
    return;
  }
  const int e0 = b * 256 + tid;
  const int gsz = 524288;                // 2048 blocks * 256 threads
  int n[4];
#pragma unroll
  for (int j = 0; j < 4; ++j) n[j] = idx[(e0 + j * gsz) >> 7];
  float inv[4];
#pragma unroll
  for (int j = 0; j < 4; ++j)
    inv[j] = 1.0f / (DECAYc * counts[n[j]] + (1.0f - DECAYc) * hist[n[j]]);
  f32x4 e4[4], d4[4];
#pragma unroll
  for (int j = 0; j < 4; ++j) {
    const int e = e0 + j * gsz;
    e4[j] = ((const f32x4*)(ema + (size_t)n[j] * Dd))[e & 127];
    d4[j] = ((const f32x4*)(dw  + (size_t)n[j] * Dd))[e & 127];
  }
#pragma unroll
  for (int j = 0; j < 4; ++j) {
    f32x4 q = (DECAYc * e4[j] + (1.0f - DECAYc) * d4[j]) * inv[j];
    __builtin_nontemporal_store(q, &((f32x4*)out_q)[e0 + j * gsz]);
  }
}

// loss = 0.5/(T*D) * (Sxx - 2*Sxq + Sqq), partials reduced in DOUBLE.
__global__ __launch_bounds__(256) void loss_final(
    const float* __restrict__ sxxp, const float* __restrict__ sxqp,
    const float* __restrict__ sqqp, float* __restrict__ out_loss) {
  const int tid = threadIdx.x;
  double acc = 0.0;
  for (int i = tid; i < 8192; i += 256) acc += (double)sxxp[i];
  for (int i = tid; i < 1024; i += 256) acc -= 2.0 * (double)sxqp[i];
  for (int i = tid; i < 1024; i += 256) acc += (double)sqqp[i];
#pragma unroll
  for (int o = 32; o; o >>= 1) acc += __shfl_down(acc, o);
  __shared__ double red[4];
  const int wd = tid >> 6, l = tid & 63;
  if (l == 0) red[wd] = acc;
  __syncthreads();
  if (tid == 0)
    *out_loss = (float)((red[0] + red[1] + red[2] + red[3]) *
                        (0.5 / ((double)Ttok * (double)Dd)));
}

// ---------------------------------------------------------------- launch
extern "C" void kernel_launch(void* const* d_in, const int* in_sizes, int n_in,
                              void* d_out, int out_size, void* d_ws, size_t ws_size,
                              hipStream_t stream) {
  const float* x      = (const float*)d_in[0];
  const float* cb     = (const float*)d_in[1];
  const float* ema    = (const float*)d_in[2];
  const float* counts = (const float*)d_in[3];

  float* out      = (float*)d_out;
  float* q_out    = out;
  float* loss_out = out + (size_t)Ttok * Dd;
  float* idxf_out = loss_out + 1;
  // d_out head reuse before quant_out overwrites it:
  //   part: float4[16][16384] = 4 MB at q_out[0 .. 1M floats)
  //   xh:   bf16 x (16.8 MB)   at q_out[2M .. 6.2M floats)   (no overlap)
  float4* part = (float4*)q_out;
  unsigned short* xh = (unsigned short*)(q_out + 2097152);

  // workspace layout (float offsets)
  float* ws = (float*)d_ws;
  unsigned short* cbh = (unsigned short*)ws;           // [0, 262144)  bf16 cb
  float* dw      = ws + 262144;                        // 524288 (zeroed in k_prep)
  float* hist    = ws + 786432;                        // 1024   (zeroed in k_prep)
  float* csq     = ws + 787460;                        // 1024
  int*   cursor  = (int*)(ws + 789508);                // 1024
  int*   bucket  = (int*)(ws + 790532);                // 16384
  int*   bcode   = (int*)(ws + 806916);                // 16384
  int*   idxb    = (int*)(ws + 823300);                // 16384
  float* sxxp    = ws + 839684;                        // 8192 (all slots written)
  float* sxqp    = ws + 847876;                        // 1024 (all slots written)
  float* sqqp    = ws + 848900;                        // 1024 (all slots written)

  k_prep<<<NB_CB + NB_Z + NB_X, 256, 0, stream>>>(cb, x, cbh, csq, xh,
                                                  (float4*)dw, sxxp);
  k_gemm_scores<<<(Nn / 128) * (Ttok / 128), 256, 0, stream>>>(cbh, xh, csq, part);
  k_select<<<Ttok / 4, 256, 0, stream>>>(part, x, cb, csq, idxb, idxf_out, hist);
  k_offsets<<<1, 256, 0, stream>>>(hist, cursor);
  k_scatter<<<Ttok / 256, 256, 0, stream>>>(idxb, cursor, bucket, bcode);
  k_dw_part<<<Ttok / CH, 512, 0, stream>>>(x, bucket, bcode, dw);
  quant_out<<<3072, 256, 0, stream>>>(ema, dw, counts, hist, idxb, q_out,
                                      sxqp, sqqp);
  loss_final<<<1, 256, 0, stream>>>(sxxp, sxqp, sqqp, loss_out);
}

// Round 19
// 111.713 us; speedup vs baseline: 2.0830x; 1.0213x over previous
//
#include <hip/hip_runtime.h>
#include <hip/hip_bf16.h>

constexpr int Dd   = 512;
constexpr int Nn   = 1024;
constexpr int Ttok = 16384;              // B*L
constexpr float DECAYc = 0.99f;
// Coarse scores are f32 MFMA of bf16-rounded inputs: error std ~0.07.
// GAP=3.0 on the EXACT coarse runner-up (top-3 store makes g1 exact).
constexpr float GAP = 3.0f;
constexpr int CH = 16;                   // tokens per dw chunk

typedef short bf16x8 __attribute__((ext_vector_type(8)));
typedef float f32x4  __attribute__((ext_vector_type(4)));

__device__ inline unsigned cvtpk(float lo, float hi) { // 2xf32 -> packed bf16
  unsigned r;
  asm("v_cvt_pk_bf16_f32 %0, %1, %2" : "=v"(r) : "v"(lo), "v"(hi));
  return r;
}

// ---- fused prep: cb->bf16 + csq (blocks 0..255), zero dw/hist/cursor2
// (blocks 256..287), x->bf16 + per-wave Sxx partials (blocks 288..2335).
// NO contended atomics (r16 lesson); per-wave partials to own slots.
constexpr int NB_CB = 256, NB_Z = 32, NB_X = 2048;
constexpr int ZF4 = 131584;              // float4s to zero (dw+hist+cursor2)
__global__ __launch_bounds__(256) void k_prep(
    const float* __restrict__ cb, const float* __restrict__ x,
    unsigned short* __restrict__ cbh, float* __restrict__ csq,
    unsigned short* __restrict__ xh, float4* __restrict__ zbase,
    float* __restrict__ sxxp) {
  const int b = blockIdx.x, tid = threadIdx.x;
  if (b < NB_CB) {
    const int n = b * 4 + (tid >> 6), l = tid & 63;
    const float4* r = (const float4*)(cb + (size_t)n * Dd);
    float4 a = r[l], c = r[l + 64];
    float ss = a.x*a.x + a.y*a.y + a.z*a.z + a.w*a.w
             + c.x*c.x + c.y*c.y + c.z*c.z + c.w*c.w;
    uint2 ua, uc;
    ua.x = cvtpk(a.x, a.y); ua.y = cvtpk(a.z, a.w);
    uc.x = cvtpk(c.x, c.y); uc.y = cvtpk(c.z, c.w);
    ((uint2*)(cbh + (size_t)n * Dd))[l]      = ua;
    ((uint2*)(cbh + (size_t)n * Dd))[l + 64] = uc;
#pragma unroll
    for (int o = 32; o; o >>= 1) ss += __shfl_down(ss, o);
    if (l == 0) csq[n] = ss;
  } else if (b < NB_CB + NB_Z) {
    const float4 z = make_float4(0.f, 0.f, 0.f, 0.f);
    for (int i = (b - NB_CB) * 256 + tid; i < ZF4; i += NB_Z * 256)
      zbase[i] = z;
  } else {
    const int bx = b - (NB_CB + NB_Z);
    float sx = 0.f;
#pragma unroll
    for (int k = 0; k < 2; ++k) {
      const int i = bx * 512 + k * 256 + tid;     // 8-float chunk id
      float4 a = ((const float4*)x)[i * 2];
      float4 c = ((const float4*)x)[i * 2 + 1];
      sx += a.x*a.x + a.y*a.y + a.z*a.z + a.w*a.w
          + c.x*c.x + c.y*c.y + c.z*c.z + c.w*c.w;
      uint4 o;
      o.x = cvtpk(a.x, a.y); o.y = cvtpk(a.z, a.w);
      o.z = cvtpk(c.x, c.y); o.w = cvtpk(c.z, c.w);
      ((uint4*)xh)[i] = o;
    }
#pragma unroll
    for (int o = 32; o; o >>= 1) sx += __shfl_down(sx, o);
    if ((tid & 63) == 0) sxxp[bx * 4 + (tid >> 6)] = sx;   // own slot, no atomic
  }
}

// ------------- MFMA GEMM, BK=32, 3-buffer 2-deep pipeline (T3/T4-lite):
// raw s_barrier + counted vmcnt(4) (never 0 in-loop) so each tile's
// global_load_lds gets TWO MFMA phases to land instead of one.
// 48 KB LDS -> 3 blocks/CU. 64B rows = conflict-free reads, linear dest.
// Fused per-64-code-half top-3 argmin epilogue (v0,v1,i0|i1,v2).
__global__ __launch_bounds__(256) void k_gemm_scores(
    const unsigned short* __restrict__ cbh, const unsigned short* __restrict__ xh,
    const float* __restrict__ csq, float4* __restrict__ part) {
  __shared__ unsigned short As[3][128 * 32];   // codes  (8 KB x3)
  __shared__ unsigned short Bs[3][128 * 32];   // tokens (8 KB x3)
  const int tid = threadIdx.x;
  const int w = tid >> 6, l = tid & 63;
  const int b = blockIdx.x;
  const int s = (b & 7) * 128 + (b >> 3);      // XCD-aware bijective swizzle
  const int cm = s & 7;        // code-block  (M)
  const int tn = s >> 3;       // token-block (N)
  const int wr = w >> 1, wc = w & 1;

  const int srow = tid >> 2;                   // 0..63 staging row
  const int scol = (tid & 3) * 8;              // elem offset of 16B chunk

  f32x4 acc[4][4] = {};

  const unsigned short* gA0 = cbh + (size_t)(cm * 128) * Dd;
  const unsigned short* gB0 = xh  + (size_t)(tn * 128) * Dd;

#define ISSUE(KC, BUF) do {                                                   \
    const int k0_ = (KC) * 32;                                                \
    _Pragma("unroll")                                                         \
    for (int p = 0; p < 2; ++p) {                                             \
      const unsigned short* ga = gA0 + (size_t)(p * 64 + srow) * Dd + k0_ + scol; \
      const unsigned short* gb = gB0 + (size_t)(p * 64 + srow) * Dd + k0_ + scol; \
      char* la = (char*)&As[BUF][0] + p * 4096 + w * 1024;                    \
      char* lb = (char*)&Bs[BUF][0] + p * 4096 + w * 1024;                    \
      __builtin_amdgcn_global_load_lds((const __attribute__((address_space(1))) void*)ga, \
                                       (__attribute__((address_space(3))) void*)la, 16, 0, 0); \
      __builtin_amdgcn_global_load_lds((const __attribute__((address_space(1))) void*)gb, \
                                       (__attribute__((address_space(3))) void*)lb, 16, 0, 0); \
    }                                                                         \
  } while (0)

  ISSUE(0, 0);
  ISSUE(1, 1);

#pragma unroll
  for (int kc = 0; kc < Dd / 32; ++kc) {
    if (kc < Dd / 32 - 1)
      asm volatile("s_waitcnt vmcnt(4)\n\ts_barrier" ::: "memory");
    else
      asm volatile("s_waitcnt vmcnt(0)\n\ts_barrier" ::: "memory");
    __builtin_amdgcn_sched_barrier(0);
    if (kc + 2 < Dd / 32) ISSUE(kc + 2, (kc + 2) % 3);
    const unsigned short* Ab = &As[kc % 3][0];
    const unsigned short* Bb = &Bs[kc % 3][0];
    const int ra = l & 15;
    const int kb = (l >> 4) * 8;               // 4 chunks spread across lanes
    bf16x8 af[4], bfr[4];
#pragma unroll
    for (int m = 0; m < 4; ++m)
      af[m] = *(const bf16x8*)&Ab[(wr * 64 + m * 16 + ra) * 32 + kb];
#pragma unroll
    for (int n = 0; n < 4; ++n)
      bfr[n] = *(const bf16x8*)&Bb[(wc * 64 + n * 16 + ra) * 32 + kb];
#pragma unroll
    for (int m = 0; m < 4; ++m)
#pragma unroll
      for (int n = 0; n < 4; ++n)
        acc[m][n] = __builtin_amdgcn_mfma_f32_16x16x32_bf16(af[m], bfr[n], acc[m][n], 0, 0, 0);
  }
#undef ISSUE

  // ------- fused per-half top-3 epilogue -------
  const int base4 = wr * 64 + (l >> 4) * 4;      // lane's local code base
  float4 cs[4];
#pragma unroll
  for (int m = 0; m < 4; ++m)
    cs[m] = *(const float4*)&csq[cm * 128 + base4 + m * 16];

  const int slot = cm * 2 + wr;                  // 0..15
  const int tok0 = tn * 128 + wc * 64 + (l & 15);

#pragma unroll
  for (int n = 0; n < 4; ++n) {
    float v0 = 3.4e38f, v1 = 3.4e38f, v2 = 3.4e38f;
    int i0 = 0x7fffffff, i1 = 0x7fffffff;
#pragma unroll
    for (int m = 0; m < 4; ++m) {
#pragma unroll
      for (int r = 0; r < 4; ++r) {
        float sv = fmaf(-2.0f, acc[m][n][r], ((const float*)&cs[m])[r]);
        int idx = cm * 128 + base4 + m * 16 + r;
        if (sv < v0)      { v2 = v1; v1 = v0; i1 = i0; v0 = sv; i0 = idx; }
        else if (sv < v1) { v2 = v1; v1 = sv; i1 = idx; }
        else if (sv < v2) { v2 = sv; }
      }
    }
#pragma unroll
    for (int o = 16; o <= 32; o <<= 1) {
      float w0 = __shfl_xor(v0, o), w1 = __shfl_xor(v1, o), w2 = __shfl_xor(v2, o);
      int  j0 = __shfl_xor(i0, o), j1 = __shfl_xor(i1, o);
      bool f = (w0 < v0) || (w0 == v0 && j0 < i0);
      float A0 = f ? w0 : v0, A1 = f ? w1 : v1, A2 = f ? w2 : v2;
      int  Ai0 = f ? j0 : i0, Ai1 = f ? j1 : i1;
      float B0 = f ? v0 : w0, B1 = f ? v1 : w1;
      int  Bi0 = f ? i0 : j0;
      bool g = (A1 < B0) || (A1 == B0 && Ai1 < Bi0);
      v0 = A0; i0 = Ai0;
      v1 = g ? A1 : B0; i1 = g ? Ai1 : Bi0;
      v2 = g ? fminf(A2, B0) : fminf(A1, B1);
    }
    if ((l >> 4) == 0)
      part[(size_t)slot * Ttok + tok0 + n * 16] = make_float4(
          v0, v1, __uint_as_float((unsigned)i0 | ((unsigned)i1 << 16)), v2);
  }
}

// exact fp32 rescore of one code (wave-cooperative), uniform n
__device__ inline void rescore(int n, const float4& xa, const float4& xb,
                               const float* __restrict__ cb,
                               const float* __restrict__ csq, int l,
                               float& bestv, int& besti) {
  const float4* cr = (const float4*)(cb + (size_t)n * Dd);
  float4 ca = cr[l * 2], cc = cr[l * 2 + 1];
  float p = xa.x*ca.x + xa.y*ca.y + xa.z*ca.z + xa.w*ca.w
          + xb.x*cc.x + xb.y*cc.y + xb.z*cc.z + xb.w*cc.w;
#pragma unroll
  for (int o = 32; o; o >>= 1) p += __shfl_xor(p, o);
  float sc = csq[n] - 2.0f * p;
  if (sc < bestv || (sc == bestv && n < besti)) { bestv = sc; besti = n; }
}

// exact rescore of a full 64-code half: one code per lane, then wave-argmin
__device__ inline void rescore_half(int h, const float* __restrict__ xrow,
                                    const float* __restrict__ cb,
                                    const float* __restrict__ csq, int l,
                                    float& bestv, int& besti) {
  int n = h * 64 + l;
  const float4* cr = (const float4*)(cb + (size_t)n * Dd);
  const float4* xr = (const float4*)xrow;
  float p = 0.f;
#pragma unroll 8
  for (int j = 0; j < 128; ++j) {
    float4 c4 = cr[j], x4 = xr[j];
    p += c4.x*x4.x + c4.y*x4.y + c4.z*x4.z + c4.w*x4.w;
  }
  float sc = csq[n] - 2.0f * p;
#pragma unroll
  for (int o = 1; o < 64; o <<= 1) {
    float ov = __shfl_xor(sc, o); int oi = __shfl_xor(n, o);
    if (ov < sc || (ov == sc && oi < n)) { sc = ov; n = oi; }
  }
  if (sc < bestv || (sc == bestv && n < besti)) { bestv = sc; besti = n; }
}

// ---- per-token: merge 16 half partials; fast path when exact coarse
// runner-up trails min by > GAP (no loads); else rescore candidates.
// NOTE (r14/r15 lesson): hist atomic stays fire-and-forget — NO barrier
// or waitcnt after any contended atomic.
__global__ __launch_bounds__(256) void k_select(
    const float4* __restrict__ part, const float* __restrict__ x,
    const float* __restrict__ cb, const float* __restrict__ csq,
    int* __restrict__ idxb, float* __restrict__ idxf, float* __restrict__ hist) {
  const int tid = threadIdx.x, wid = tid >> 6, l = tid & 63;
  const int t = blockIdx.x * 4 + wid;
  float v0 = 3.4e38f, v1 = 3.4e38f, v2 = 3.4e38f;
  int i0 = 0x7fffffff, i1 = 0x7fffffff;
  if (l < 16) {
    float4 e = part[(size_t)l * Ttok + t];
    v0 = e.x; v1 = e.y; v2 = e.w;
    unsigned ii = __float_as_uint(e.z);
    i0 = (int)(ii & 0xffff); i1 = (int)(ii >> 16);
  }
  float A0 = v0, A1 = v1; int Ai0 = i0, Ai1 = i1;
#pragma unroll
  for (int o = 1; o < 16; o <<= 1) {
    float w0 = __shfl_xor(A0, o), w1 = __shfl_xor(A1, o);
    int  j0 = __shfl_xor(Ai0, o), j1 = __shfl_xor(Ai1, o);
    bool f = (w0 < A0) || (w0 == A0 && j0 < Ai0);
    float B0 = f ? A0 : w0; int Bi0 = f ? Ai0 : j0;
    float W1 = f ? w1 : A1; int Wi1 = f ? j1 : Ai1;
    if (f) { A0 = w0; Ai0 = j0; }
    bool g = (B0 < W1) || (B0 == W1 && Bi0 < Wi1);
    A1 = g ? B0 : W1; Ai1 = g ? Bi0 : Wi1;
  }
  const float m  = __shfl(A0, 0);
  const float g1 = __shfl(A1, 0);
  const int   gi = __shfl(Ai0, 0);
  int besti;
  if (g1 - m > GAP) {
    besti = gi;
  } else {
    const float thr = m + GAP;
    const float* xrow = x + (size_t)t * Dd;
    const float4* xr = (const float4*)xrow;
    float4 xa = xr[l * 2], xb = xr[l * 2 + 1];
    float bestv = 3.4e38f; besti = 0x7fffffff;
    for (int h = 0; h < 16; ++h) {
      float b0 = __shfl(v0, h);
      if (b0 > thr) continue;
      float b1 = __shfl(v1, h), b2 = __shfl(v2, h);
      int bi0 = __shfl(i0, h), bi1 = __shfl(i1, h);
      if (b2 <= thr) {
        rescore_half(h, xrow, cb, csq, l, bestv, besti);
      } else {
        rescore(bi0, xa, xb, cb, csq, l, bestv, besti);
        if (b1 <= thr) rescore(bi1, xa, xb, cb, csq, l, bestv, besti);
      }
    }
  }
  if (l == 0) {
    idxb[t] = besti;
    idxf[t] = (float)besti;
    atomicAdd(&hist[besti], 1.0f);
  }
}

// ---- bucket tokens by code. Each block computes the SAME hist->offs
// exclusive prefix redundantly in LDS (absorbs old k_offsets kernel),
// then scatters its 256 tokens with offs[n] + atomicAdd(cursor2[n],1).
// Order within a code's range is arbitrary — dw's segmented sum is
// order-tolerant (proven since r3).
__global__ __launch_bounds__(256) void k_scatter(
    const int* __restrict__ idxb, const float* __restrict__ hist,
    int* __restrict__ cursor2, int* __restrict__ bucket,
    int* __restrict__ bcode) {
  __shared__ int offs[1024];
  __shared__ int wsum[4];
  const int tid = threadIdx.x, l = tid & 63, wd = tid >> 6;
  const int base = tid * 4;
  int c0 = (int)hist[base], c1 = (int)hist[base + 1],
      c2 = (int)hist[base + 2], c3 = (int)hist[base + 3];
  int sum = c0 + c1 + c2 + c3;
  int sc = sum;
#pragma unroll
  for (int o = 1; o < 64; o <<= 1) { int v = __shfl_up(sc, o); if (l >= o) sc += v; }
  if (l == 63) wsum[wd] = sc;
  __syncthreads();
  int wbase = 0;
  for (int i = 0; i < wd; ++i) wbase += wsum[i];
  int e = wbase + sc - sum;
  offs[base]     = e;
  offs[base + 1] = e + c0;
  offs[base + 2] = e + c0 + c1;
  offs[base + 3] = e + c0 + c1 + c2;
  __syncthreads();
  const int t = blockIdx.x * 256 + tid;
  const int n = idxb[t];
  const int p = offs[n] + atomicAdd(&cursor2[n], 1);
  bucket[p] = t;
  bcode[p] = n;
}

// ------- load-balanced segmented sum: dw[n][d] += x rows of chunk segments
__global__ __launch_bounds__(512) void k_dw_part(
    const float* __restrict__ x, const int* __restrict__ bucket,
    const int* __restrict__ bcode, float* __restrict__ dw) {
  __shared__ int sh_t[CH], sh_n[CH];
  const int tid = threadIdx.x;
  const int p0 = blockIdx.x * CH;
  if (tid < CH) { sh_t[tid] = bucket[p0 + tid]; sh_n[tid] = bcode[p0 + tid]; }
  __syncthreads();
  float v[CH];
#pragma unroll
  for (int j = 0; j < CH; ++j)
    v[j] = x[(size_t)sh_t[j] * Dd + tid];
  float acc = v[0]; int cur = sh_n[0];
#pragma unroll
  for (int j = 1; j < CH; ++j) {
    int n = sh_n[j];
    if (n != cur) { atomicAdd(&dw[(size_t)cur * Dd + tid], acc); acc = 0.f; cur = n; }
    acc += v[j];
  }
  atomicAdd(&dw[(size_t)cur * Dd + tid], acc);
}

// ------- quantized gather + per-code loss terms MERGED in one launch.
// Blocks [0,2048): quantized = (decay*ema[idx]+(1-decay)*dw[idx])/cnt[idx]
// (pure gather + NT stream write, no x read). Blocks [2048,3072): per-code
// sxqp/sqqp partials (plain stores, no atomics).
__global__ __launch_bounds__(256) void quant_out(
    const float* __restrict__ ema, const float* __restrict__ dw,
    const float* __restrict__ counts, const float* __restrict__ hist,
    const int* __restrict__ idx, float* __restrict__ out_q,
    float* __restrict__ sxqp, float* __restrict__ sqqp) {
  const int b = blockIdx.x, tid = threadIdx.x;
  if (b >= 2048) {                       // ---- loss-terms blocks ----
    const int n = b - 2048;
    if (tid < 128) {
      const float hc = hist[n];
      const float inv = 1.0f / (DECAYc * counts[n] + (1.0f - DECAYc) * hc);
      f32x4 e = ((const f32x4*)(ema + (size_t)n * Dd))[tid];
      f32x4 d = ((const f32x4*)(dw  + (size_t)n * Dd))[tid];
      f32x4 q = (DECAYc * e + (1.0f - DECAYc) * d) * inv;
      float xq = q[0]*d[0] + q[1]*d[1] + q[2]*d[2] + q[3]*d[3];
      float qq = q[0]*q[0] + q[1]*q[1] + q[2]*q[2] + q[3]*q[3];
#pragma unroll
      for (int o = 32; o; o >>= 1) { xq += __shfl_down(xq, o); qq += __shfl_down(qq, o); }
      __shared__ float sx[2], sq[2];
      const int wd = tid >> 6, l = tid & 63;
      if (l == 0) { sx[wd] = xq; sq[wd] = qq; }
      __syncthreads();
      if (tid == 0) { sxqp[n] = sx[0] + sx[1]; sqqp[n] = hc * (sq[0] + sq[1]); }
    }
    return;
  }
  const int e0 = b * 256 + tid;
  const int gsz = 524288;                // 2048 blocks * 256 threads
  int n[4];
#pragma unroll
  for (int j = 0; j < 4; ++j) n[j] = idx[(e0 + j * gsz) >> 7];
  float inv[4];
#pragma unroll
  for (int j = 0; j < 4; ++j)
    inv[j] = 1.0f / (DECAYc * counts[n[j]] + (1.0f - DECAYc) * hist[n[j]]);
  f32x4 e4[4], d4[4];
#pragma unroll
  for (int j = 0; j < 4; ++j) {
    const int e = e0 + j * gsz;
    e4[j] = ((const f32x4*)(ema + (size_t)n[j] * Dd))[e & 127];
    d4[j] = ((const f32x4*)(dw  + (size_t)n[j] * Dd))[e & 127];
  }
#pragma unroll
  for (int j = 0; j < 4; ++j) {
    f32x4 q = (DECAYc * e4[j] + (1.0f - DECAYc) * d4[j]) * inv[j];
    __builtin_nontemporal_store(q, &((f32x4*)out_q)[e0 + j * gsz]);
  }
}

// loss = 0.5/(T*D) * (Sxx - 2*Sxq + Sqq), partials reduced in DOUBLE.
__global__ __launch_bounds__(256) void loss_final(
    const float* __restrict__ sxxp, const float* __restrict__ sxqp,
    const float* __restrict__ sqqp, float* __restrict__ out_loss) {
  const int tid = threadIdx.x;
  double acc = 0.0;
  for (int i = tid; i < 8192; i += 256) acc += (double)sxxp[i];
  for (int i = tid; i < 1024; i += 256) acc -= 2.0 * (double)sxqp[i];
  for (int i = tid; i < 1024; i += 256) acc += (double)sqqp[i];
#pragma unroll
  for (int o = 32; o; o >>= 1) acc += __shfl_down(acc, o);
  __shared__ double red[4];
  const int wd = tid >> 6, l = tid & 63;
  if (l == 0) red[wd] = acc;
  __syncthreads();
  if (tid == 0)
    *out_loss = (float)((red[0] + red[1] + red[2] + red[3]) *
                        (0.5 / ((double)Ttok * (double)Dd)));
}

// ---------------------------------------------------------------- launch
extern "C" void kernel_launch(void* const* d_in, const int* in_sizes, int n_in,
                              void* d_out, int out_size, void* d_ws, size_t ws_size,
                              hipStream_t stream) {
  const float* x      = (const float*)d_in[0];
  const float* cb     = (const float*)d_in[1];
  const float* ema    = (const float*)d_in[2];
  const float* counts = (const float*)d_in[3];

  float* out      = (float*)d_out;
  float* q_out    = out;
  float* loss_out = out + (size_t)Ttok * Dd;
  float* idxf_out = loss_out + 1;
  // d_out head reuse before quant_out overwrites it:
  //   part: float4[16][16384] = 4 MB at q_out[0 .. 1M floats)
  //   xh:   bf16 x (16.8 MB)   at q_out[2M .. 6.2M floats)   (no overlap)
  float4* part = (float4*)q_out;
  unsigned short* xh = (unsigned short*)(q_out + 2097152);

  // workspace layout (float offsets)
  float* ws = (float*)d_ws;
  unsigned short* cbh = (unsigned short*)ws;           // [0, 262144)  bf16 cb
  float* dw      = ws + 262144;                        // 524288 (zeroed in k_prep)
  float* hist    = ws + 786432;                        // 1024   (zeroed in k_prep)
  int*   cursor2 = (int*)(ws + 787456);                // 1024   (zeroed in k_prep)
  float* csq     = ws + 788480;                        // 1024
  int*   bucket  = (int*)(ws + 789504);                // 16384
  int*   bcode   = (int*)(ws + 805888);                // 16384
  int*   idxb    = (int*)(ws + 822272);                // 16384
  float* sxxp    = ws + 838656;                        // 8192 (all slots written)
  float* sxqp    = ws + 846848;                        // 1024 (all slots written)
  float* sqqp    = ws + 847872;                        // 1024 (all slots written)

  k_prep<<<NB_CB + NB_Z + NB_X, 256, 0, stream>>>(cb, x, cbh, csq, xh,
                                                  (float4*)dw, sxxp);
  k_gemm_scores<<<(Nn / 128) * (Ttok / 128), 256, 0, stream>>>(cbh, xh, csq, part);
  k_select<<<Ttok / 4, 256, 0, stream>>>(part, x, cb, csq, idxb, idxf_out, hist);
  k_scatter<<<Ttok / 256, 256, 0, stream>>>(idxb, hist, cursor2, bucket, bcode);
  k_dw_part<<<Ttok / CH, 512, 0, stream>>>(x, bucket, bcode, dw);
  quant_out<<<3072, 256, 0, stream>>>(ema, dw, counts, hist, idxb, q_out,
                                      sxqp, sqqp);
  loss_final<<<1, 256, 0, stream>>>(sxxp, sxqp, sqqp, loss_out);
}

// Round 20
// 111.083 us; speedup vs baseline: 2.0949x; 1.0057x over previous
//
#include <hip/hip_runtime.h>
#include <hip/hip_bf16.h>

constexpr int Dd   = 512;
constexpr int Nn   = 1024;
constexpr int Ttok = 16384;              // B*L
constexpr float DECAYc = 0.99f;
// Coarse scores are f32 MFMA of bf16-rounded inputs: error std ~0.07.
// GAP=3.0 on the EXACT coarse runner-up (top-3 store makes g1 exact).
constexpr float GAP = 3.0f;
constexpr int CH = 32;                   // tokens per dw chunk (r20: 16->32)

typedef short bf16x8 __attribute__((ext_vector_type(8)));
typedef float f32x4  __attribute__((ext_vector_type(4)));

__device__ inline unsigned cvtpk(float lo, float hi) { // 2xf32 -> packed bf16
  unsigned r;
  asm("v_cvt_pk_bf16_f32 %0, %1, %2" : "=v"(r) : "v"(lo), "v"(hi));
  return r;
}

// ---- fused prep: cb->bf16 + csq (blocks 0..255), zero dw/hist/cursor2
// (blocks 256..287), x->bf16 + per-wave Sxx partials (blocks 288..2335).
// NO contended atomics (r16 lesson); per-wave partials to own slots.
constexpr int NB_CB = 256, NB_Z = 32, NB_X = 2048;
constexpr int ZF4 = 131584;              // float4s to zero (dw+hist+cursor2)
__global__ __launch_bounds__(256) void k_prep(
    const float* __restrict__ cb, const float* __restrict__ x,
    unsigned short* __restrict__ cbh, float* __restrict__ csq,
    unsigned short* __restrict__ xh, float4* __restrict__ zbase,
    float* __restrict__ sxxp) {
  const int b = blockIdx.x, tid = threadIdx.x;
  if (b < NB_CB) {
    const int n = b * 4 + (tid >> 6), l = tid & 63;
    const float4* r = (const float4*)(cb + (size_t)n * Dd);
    float4 a = r[l], c = r[l + 64];
    float ss = a.x*a.x + a.y*a.y + a.z*a.z + a.w*a.w
             + c.x*c.x + c.y*c.y + c.z*c.z + c.w*c.w;
    uint2 ua, uc;
    ua.x = cvtpk(a.x, a.y); ua.y = cvtpk(a.z, a.w);
    uc.x = cvtpk(c.x, c.y); uc.y = cvtpk(c.z, c.w);
    ((uint2*)(cbh + (size_t)n * Dd))[l]      = ua;
    ((uint2*)(cbh + (size_t)n * Dd))[l + 64] = uc;
#pragma unroll
    for (int o = 32; o; o >>= 1) ss += __shfl_down(ss, o);
    if (l == 0) csq[n] = ss;
  } else if (b < NB_CB + NB_Z) {
    const float4 z = make_float4(0.f, 0.f, 0.f, 0.f);
    for (int i = (b - NB_CB) * 256 + tid; i < ZF4; i += NB_Z * 256)
      zbase[i] = z;
  } else {
    const int bx = b - (NB_CB + NB_Z);
    float sx = 0.f;
#pragma unroll
    for (int k = 0; k < 2; ++k) {
      const int i = bx * 512 + k * 256 + tid;     // 8-float chunk id
      float4 a = ((const float4*)x)[i * 2];
      float4 c = ((const float4*)x)[i * 2 + 1];
      sx += a.x*a.x + a.y*a.y + a.z*a.z + a.w*a.w
          + c.x*c.x + c.y*c.y + c.z*c.z + c.w*c.w;
      uint4 o;
      o.x = cvtpk(a.x, a.y); o.y = cvtpk(a.z, a.w);
      o.z = cvtpk(c.x, c.y); o.w = cvtpk(c.z, c.w);
      ((uint4*)xh)[i] = o;
    }
#pragma unroll
    for (int o = 32; o; o >>= 1) sx += __shfl_down(sx, o);
    if ((tid & 63) == 0) sxxp[bx * 4 + (tid >> 6)] = sx;   // own slot, no atomic
  }
}

// ------------- MFMA GEMM, BK=32, 3-buffer 2-deep pipeline (T3/T4-lite):
// raw s_barrier + counted vmcnt(4) (never 0 in-loop) so each tile's
// global_load_lds gets TWO MFMA phases to land instead of one.
// 48 KB LDS -> 3 blocks/CU. 64B rows = conflict-free reads, linear dest.
// Fused per-64-code-half top-3 argmin epilogue (v0,v1,i0|i1,v2).
__global__ __launch_bounds__(256) void k_gemm_scores(
    const unsigned short* __restrict__ cbh, const unsigned short* __restrict__ xh,
    const float* __restrict__ csq, float4* __restrict__ part) {
  __shared__ unsigned short As[3][128 * 32];   // codes  (8 KB x3)
  __shared__ unsigned short Bs[3][128 * 32];   // tokens (8 KB x3)
  const int tid = threadIdx.x;
  const int w = tid >> 6, l = tid & 63;
  const int b = blockIdx.x;
  const int s = (b & 7) * 128 + (b >> 3);      // XCD-aware bijective swizzle
  const int cm = s & 7;        // code-block  (M)
  const int tn = s >> 3;       // token-block (N)
  const int wr = w >> 1, wc = w & 1;

  const int srow = tid >> 2;                   // 0..63 staging row
  const int scol = (tid & 3) * 8;              // elem offset of 16B chunk

  f32x4 acc[4][4] = {};

  const unsigned short* gA0 = cbh + (size_t)(cm * 128) * Dd;
  const unsigned short* gB0 = xh  + (size_t)(tn * 128) * Dd;

#define ISSUE(KC, BUF) do {                                                   \
    const int k0_ = (KC) * 32;                                                \
    _Pragma("unroll")                                                         \
    for (int p = 0; p < 2; ++p) {                                             \
      const unsigned short* ga = gA0 + (size_t)(p * 64 + srow) * Dd + k0_ + scol; \
      const unsigned short* gb = gB0 + (size_t)(p * 64 + srow) * Dd + k0_ + scol; \
      char* la = (char*)&As[BUF][0] + p * 4096 + w * 1024;                    \
      char* lb = (char*)&Bs[BUF][0] + p * 4096 + w * 1024;                    \
      __builtin_amdgcn_global_load_lds((const __attribute__((address_space(1))) void*)ga, \
                                       (__attribute__((address_space(3))) void*)la, 16, 0, 0); \
      __builtin_amdgcn_global_load_lds((const __attribute__((address_space(1))) void*)gb, \
                                       (__attribute__((address_space(3))) void*)lb, 16, 0, 0); \
    }                                                                         \
  } while (0)

  ISSUE(0, 0);
  ISSUE(1, 1);

#pragma unroll
  for (int kc = 0; kc < Dd / 32; ++kc) {
    if (kc < Dd / 32 - 1)
      asm volatile("s_waitcnt vmcnt(4)\n\ts_barrier" ::: "memory");
    else
      asm volatile("s_waitcnt vmcnt(0)\n\ts_barrier" ::: "memory");
    __builtin_amdgcn_sched_barrier(0);
    if (kc + 2 < Dd / 32) ISSUE(kc + 2, (kc + 2) % 3);
    const unsigned short* Ab = &As[kc % 3][0];
    const unsigned short* Bb = &Bs[kc % 3][0];
    const int ra = l & 15;
    const int kb = (l >> 4) * 8;               // 4 chunks spread across lanes
    bf16x8 af[4], bfr[4];
#pragma unroll
    for (int m = 0; m < 4; ++m)
      af[m] = *(const bf16x8*)&Ab[(wr * 64 + m * 16 + ra) * 32 + kb];
#pragma unroll
    for (int n = 0; n < 4; ++n)
      bfr[n] = *(const bf16x8*)&Bb[(wc * 64 + n * 16 + ra) * 32 + kb];
#pragma unroll
    for (int m = 0; m < 4; ++m)
#pragma unroll
      for (int n = 0; n < 4; ++n)
        acc[m][n] = __builtin_amdgcn_mfma_f32_16x16x32_bf16(af[m], bfr[n], acc[m][n], 0, 0, 0);
  }
#undef ISSUE

  // ------- fused per-half top-3 epilogue -------
  const int base4 = wr * 64 + (l >> 4) * 4;      // lane's local code base
  float4 cs[4];
#pragma unroll
  for (int m = 0; m < 4; ++m)
    cs[m] = *(const float4*)&csq[cm * 128 + base4 + m * 16];

  const int slot = cm * 2 + wr;                  // 0..15
  const int tok0 = tn * 128 + wc * 64 + (l & 15);

#pragma unroll
  for (int n = 0; n < 4; ++n) {
    float v0 = 3.4e38f, v1 = 3.4e38f, v2 = 3.4e38f;
    int i0 = 0x7fffffff, i1 = 0x7fffffff;
#pragma unroll
    for (int m = 0; m < 4; ++m) {
#pragma unroll
      for (int r = 0; r < 4; ++r) {
        float sv = fmaf(-2.0f, acc[m][n][r], ((const float*)&cs[m])[r]);
        int idx = cm * 128 + base4 + m * 16 + r;
        if (sv < v0)      { v2 = v1; v1 = v0; i1 = i0; v0 = sv; i0 = idx; }
        else if (sv < v1) { v2 = v1; v1 = sv; i1 = idx; }
        else if (sv < v2) { v2 = sv; }
      }
    }
#pragma unroll
    for (int o = 16; o <= 32; o <<= 1) {
      float w0 = __shfl_xor(v0, o), w1 = __shfl_xor(v1, o), w2 = __shfl_xor(v2, o);
      int  j0 = __shfl_xor(i0, o), j1 = __shfl_xor(i1, o);
      bool f = (w0 < v0) || (w0 == v0 && j0 < i0);
      float A0 = f ? w0 : v0, A1 = f ? w1 : v1, A2 = f ? w2 : v2;
      int  Ai0 = f ? j0 : i0, Ai1 = f ? j1 : i1;
      float B0 = f ? v0 : w0, B1 = f ? v1 : w1;
      int  Bi0 = f ? i0 : j0;
      bool g = (A1 < B0) || (A1 == B0 && Ai1 < Bi0);
      v0 = A0; i0 = Ai0;
      v1 = g ? A1 : B0; i1 = g ? Ai1 : Bi0;
      v2 = g ? fminf(A2, B0) : fminf(A1, B1);
    }
    if ((l >> 4) == 0)
      part[(size_t)slot * Ttok + tok0 + n * 16] = make_float4(
          v0, v1, __uint_as_float((unsigned)i0 | ((unsigned)i1 << 16)), v2);
  }
}

// exact fp32 rescore of one code (wave-cooperative), uniform n
__device__ inline void rescore(int n, const float4& xa, const float4& xb,
                               const float* __restrict__ cb,
                               const float* __restrict__ csq, int l,
                               float& bestv, int& besti) {
  const float4* cr = (const float4*)(cb + (size_t)n * Dd);
  float4 ca = cr[l * 2], cc = cr[l * 2 + 1];
  float p = xa.x*ca.x + xa.y*ca.y + xa.z*ca.z + xa.w*ca.w
          + xb.x*cc.x + xb.y*cc.y + xb.z*cc.z + xb.w*cc.w;
#pragma unroll
  for (int o = 32; o; o >>= 1) p += __shfl_xor(p, o);
  float sc = csq[n] - 2.0f * p;
  if (sc < bestv || (sc == bestv && n < besti)) { bestv = sc; besti = n; }
}

// exact rescore of a full 64-code half: one code per lane, then wave-argmin
__device__ inline void rescore_half(int h, const float* __restrict__ xrow,
                                    const float* __restrict__ cb,
                                    const float* __restrict__ csq, int l,
                                    float& bestv, int& besti) {
  int n = h * 64 + l;
  const float4* cr = (const float4*)(cb + (size_t)n * Dd);
  const float4* xr = (const float4*)xrow;
  float p = 0.f;
#pragma unroll 8
  for (int j = 0; j < 128; ++j) {
    float4 c4 = cr[j], x4 = xr[j];
    p += c4.x*x4.x + c4.y*x4.y + c4.z*x4.z + c4.w*x4.w;
  }
  float sc = csq[n] - 2.0f * p;
#pragma unroll
  for (int o = 1; o < 64; o <<= 1) {
    float ov = __shfl_xor(sc, o); int oi = __shfl_xor(n, o);
    if (ov < sc || (ov == sc && oi < n)) { sc = ov; n = oi; }
  }
  if (sc < bestv || (sc == bestv && n < besti)) { bestv = sc; besti = n; }
}

// ---- per-token: merge 16 half partials; fast path when exact coarse
// runner-up trails min by > GAP (no loads); else rescore candidates.
// NOTE (r14/r15 lesson): hist atomic stays fire-and-forget — NO barrier
// or waitcnt after any contended atomic.
__global__ __launch_bounds__(256) void k_select(
    const float4* __restrict__ part, const float* __restrict__ x,
    const float* __restrict__ cb, const float* __restrict__ csq,
    int* __restrict__ idxb, float* __restrict__ idxf, float* __restrict__ hist) {
  const int tid = threadIdx.x, wid = tid >> 6, l = tid & 63;
  const int t = blockIdx.x * 4 + wid;
  float v0 = 3.4e38f, v1 = 3.4e38f, v2 = 3.4e38f;
  int i0 = 0x7fffffff, i1 = 0x7fffffff;
  if (l < 16) {
    float4 e = part[(size_t)l * Ttok + t];
    v0 = e.x; v1 = e.y; v2 = e.w;
    unsigned ii = __float_as_uint(e.z);
    i0 = (int)(ii & 0xffff); i1 = (int)(ii >> 16);
  }
  float A0 = v0, A1 = v1; int Ai0 = i0, Ai1 = i1;
#pragma unroll
  for (int o = 1; o < 16; o <<= 1) {
    float w0 = __shfl_xor(A0, o), w1 = __shfl_xor(A1, o);
    int  j0 = __shfl_xor(Ai0, o), j1 = __shfl_xor(Ai1, o);
    bool f = (w0 < A0) || (w0 == A0 && j0 < Ai0);
    float B0 = f ? A0 : w0; int Bi0 = f ? Ai0 : j0;
    float W1 = f ? w1 : A1; int Wi1 = f ? j1 : Ai1;
    if (f) { A0 = w0; Ai0 = j0; }
    bool g = (B0 < W1) || (B0 == W1 && Bi0 < Wi1);
    A1 = g ? B0 : W1; Ai1 = g ? Bi0 : Wi1;
  }
  const float m  = __shfl(A0, 0);
  const float g1 = __shfl(A1, 0);
  const int   gi = __shfl(Ai0, 0);
  int besti;
  if (g1 - m > GAP) {
    besti = gi;
  } else {
    const float thr = m + GAP;
    const float* xrow = x + (size_t)t * Dd;
    const float4* xr = (const float4*)xrow;
    float4 xa = xr[l * 2], xb = xr[l * 2 + 1];
    float bestv = 3.4e38f; besti = 0x7fffffff;
    for (int h = 0; h < 16; ++h) {
      float b0 = __shfl(v0, h);
      if (b0 > thr) continue;
      float b1 = __shfl(v1, h), b2 = __shfl(v2, h);
      int bi0 = __shfl(i0, h), bi1 = __shfl(i1, h);
      if (b2 <= thr) {
        rescore_half(h, xrow, cb, csq, l, bestv, besti);
      } else {
        rescore(bi0, xa, xb, cb, csq, l, bestv, besti);
        if (b1 <= thr) rescore(bi1, xa, xb, cb, csq, l, bestv, besti);
      }
    }
  }
  if (l == 0) {
    idxb[t] = besti;
    idxf[t] = (float)besti;
    atomicAdd(&hist[besti], 1.0f);
  }
}

// ---- bucket tokens by code. Each block computes the SAME hist->offs
// exclusive prefix redundantly in LDS (absorbed k_offsets), then scatters
// its 256 tokens with offs[n] + atomicAdd(cursor2[n],1).
__global__ __launch_bounds__(256) void k_scatter(
    const int* __restrict__ idxb, const float* __restrict__ hist,
    int* __restrict__ cursor2, int* __restrict__ bucket,
    int* __restrict__ bcode) {
  __shared__ int offs[1024];
  __shared__ int wsum[4];
  const int tid = threadIdx.x, l = tid & 63, wd = tid >> 6;
  const int base = tid * 4;
  int c0 = (int)hist[base], c1 = (int)hist[base + 1],
      c2 = (int)hist[base + 2], c3 = (int)hist[base + 3];
  int sum = c0 + c1 + c2 + c3;
  int sc = sum;
#pragma unroll
  for (int o = 1; o < 64; o <<= 1) { int v = __shfl_up(sc, o); if (l >= o) sc += v; }
  if (l == 63) wsum[wd] = sc;
  __syncthreads();
  int wbase = 0;
  for (int i = 0; i < wd; ++i) wbase += wsum[i];
  int e = wbase + sc - sum;
  offs[base]     = e;
  offs[base + 1] = e + c0;
  offs[base + 2] = e + c0 + c1;
  offs[base + 3] = e + c0 + c1 + c2;
  __syncthreads();
  const int t = blockIdx.x * 256 + tid;
  const int n = idxb[t];
  const int p = offs[n] + atomicAdd(&cursor2[n], 1);
  bucket[p] = t;
  bcode[p] = n;
}

// ------- load-balanced segmented sum: dw[n][d] += x rows of chunk segments
// CH=32 (r20): half the blocks, ~25% fewer flush atomics, 32 loads in flight.
__global__ __launch_bounds__(512) void k_dw_part(
    const float* __restrict__ x, const int* __restrict__ bucket,
    const int* __restrict__ bcode, float* __restrict__ dw) {
  __shared__ int sh_t[CH], sh_n[CH];
  const int tid = threadIdx.x;
  const int p0 = blockIdx.x * CH;
  if (tid < CH) { sh_t[tid] = bucket[p0 + tid]; sh_n[tid] = bcode[p0 + tid]; }
  __syncthreads();
  float v[CH];
#pragma unroll
  for (int j = 0; j < CH; ++j)
    v[j] = x[(size_t)sh_t[j] * Dd + tid];
  float acc = v[0]; int cur = sh_n[0];
#pragma unroll
  for (int j = 1; j < CH; ++j) {
    int n = sh_n[j];
    if (n != cur) { atomicAdd(&dw[(size_t)cur * Dd + tid], acc); acc = 0.f; cur = n; }
    acc += v[j];
  }
  atomicAdd(&dw[(size_t)cur * Dd + tid], acc);
}

// ------- quantized gather + per-code loss terms MERGED in one launch.
// Blocks [0,2048): quantized = (decay*ema[idx]+(1-decay)*dw[idx])/cnt[idx]
// (pure gather + NT stream write, no x read). Blocks [2048,2560): per-code
// sxqp/sqqp partials, 2 codes per block (full 256 threads busy).
__global__ __launch_bounds__(256) void quant_out(
    const float* __restrict__ ema, const float* __restrict__ dw,
    const float* __restrict__ counts, const float* __restrict__ hist,
    const int* __restrict__ idx, float* __restrict__ out_q,
    float* __restrict__ sxqp, float* __restrict__ sqqp) {
  const int b = blockIdx.x, tid = threadIdx.x;
  if (b >= 2048) {                       // ---- loss-terms blocks ----
    const int n = (b - 2048) * 2 + (tid >> 7);   // 2 codes per block
    const int lt = tid & 127;
    const float hc = hist[n];
    const float inv = 1.0f / (DECAYc * counts[n] + (1.0f - DECAYc) * hc);
    f32x4 e = ((const f32x4*)(ema + (size_t)n * Dd))[lt];
    f32x4 d = ((const f32x4*)(dw  + (size_t)n * Dd))[lt];
    f32x4 q = (DECAYc * e + (1.0f - DECAYc) * d) * inv;
    float xq = q[0]*d[0] + q[1]*d[1] + q[2]*d[2] + q[3]*d[3];
    float qq = q[0]*q[0] + q[1]*q[1] + q[2]*q[2] + q[3]*q[3];
#pragma unroll
    for (int o = 32; o; o >>= 1) { xq += __shfl_down(xq, o); qq += __shfl_down(qq, o); }
    __shared__ float sx[4], sq[4];
    const int wd = tid >> 6, l = tid & 63;
    if (l == 0) { sx[wd] = xq; sq[wd] = qq; }
    __syncthreads();
    if (lt == 0) {
      const int w0 = (tid >> 7) * 2;             // waves of this half
      sxqp[n] = sx[w0] + sx[w0 + 1];
      sqqp[n] = hc * (sq[w0] + sq[w0 + 1]);
    }
    return;
  }
  const int e0 = b * 256 + tid;
  const int gsz = 524288;                // 2048 blocks * 256 threads
  int n[4];
#pragma unroll
  for (int j = 0; j < 4; ++j) n[j] = idx[(e0 + j * gsz) >> 7];
  float inv[4];
#pragma unroll
  for (int j = 0; j < 4; ++j)
    inv[j] = 1.0f / (DECAYc * counts[n[j]] + (1.0f - DECAYc) * hist[n[j]]);
  f32x4 e4[4], d4[4];
#pragma unroll
  for (int j = 0; j < 4; ++j) {
    const int e = e0 + j * gsz;
    e4[j] = ((const f32x4*)(ema + (size_t)n[j] * Dd))[e & 127];
    d4[j] = ((const f32x4*)(dw  + (size_t)n[j] * Dd))[e & 127];
  }
#pragma unroll
  for (int j = 0; j < 4; ++j) {
    f32x4 q = (DECAYc * e4[j] + (1.0f - DECAYc) * d4[j]) * inv[j];
    __builtin_nontemporal_store(q, &((f32x4*)out_q)[e0 + j * gsz]);
  }
}

// loss = 0.5/(T*D) * (Sxx - 2*Sxq + Sqq), partials reduced in DOUBLE.
__global__ __launch_bounds__(256) void loss_final(
    const float* __restrict__ sxxp, const float* __restrict__ sxqp,
    const float* __restrict__ sqqp, float* __restrict__ out_loss) {
  const int tid = threadIdx.x;
  double acc = 0.0;
  for (int i = tid; i < 8192; i += 256) acc += (double)sxxp[i];
  for (int i = tid; i < 1024; i += 256) acc -= 2.0 * (double)sxqp[i];
  for (int i = tid; i < 1024; i += 256) acc += (double)sqqp[i];
#pragma unroll
  for (int o = 32; o; o >>= 1) acc += __shfl_down(acc, o);
  __shared__ double red[4];
  const int wd = tid >> 6, l = tid & 63;
  if (l == 0) red[wd] = acc;
  __syncthreads();
  if (tid == 0)
    *out_loss = (float)((red[0] + red[1] + red[2] + red[3]) *
                        (0.5 / ((double)Ttok * (double)Dd)));
}

// ---------------------------------------------------------------- launch
extern "C" void kernel_launch(void* const* d_in, const int* in_sizes, int n_in,
                              void* d_out, int out_size, void* d_ws, size_t ws_size,
                              hipStream_t stream) {
  const float* x      = (const float*)d_in[0];
  const float* cb     = (const float*)d_in[1];
  const float* ema    = (const float*)d_in[2];
  const float* counts = (const float*)d_in[3];

  float* out      = (float*)d_out;
  float* q_out    = out;
  float* loss_out = out + (size_t)Ttok * Dd;
  float* idxf_out = loss_out + 1;
  // d_out head reuse before quant_out overwrites it:
  //   part: float4[16][16384] = 4 MB at q_out[0 .. 1M floats)
  //   xh:   bf16 x (16.8 MB)   at q_out[2M .. 6.2M floats)   (no overlap)
  float4* part = (float4*)q_out;
  unsigned short* xh = (unsigned short*)(q_out + 2097152);

  // workspace layout (float offsets)
  float* ws = (float*)d_ws;
  unsigned short* cbh = (unsigned short*)ws;           // [0, 262144)  bf16 cb
  float* dw      = ws + 262144;                        // 524288 (zeroed in k_prep)
  float* hist    = ws + 786432;                        // 1024   (zeroed in k_prep)
  int*   cursor2 = (int*)(ws + 787456);                // 1024   (zeroed in k_prep)
  float* csq     = ws + 788480;                        // 1024
  int*   bucket  = (int*)(ws + 789504);                // 16384
  int*   bcode   = (int*)(ws + 805888);                // 16384
  int*   idxb    = (int*)(ws + 822272);                // 16384
  float* sxxp    = ws + 838656;                        // 8192 (all slots written)
  float* sxqp    = ws + 846848;                        // 1024 (all slots written)
  float* sqqp    = ws + 847872;                        // 1024 (all slots written)

  k_prep<<<NB_CB + NB_Z + NB_X, 256, 0, stream>>>(cb, x, cbh, csq, xh,
                                                  (float4*)dw, sxxp);
  k_gemm_scores<<<(Nn / 128) * (Ttok / 128), 256, 0, stream>>>(cbh, xh, csq, part);
  k_select<<<Ttok / 4, 256, 0, stream>>>(part, x, cb, csq, idxb, idxf_out, hist);
  k_scatter<<<Ttok / 256, 256, 0, stream>>>(idxb, hist, cursor2, bucket, bcode);
  k_dw_part<<<Ttok / CH, 512, 0, stream>>>(x, bucket, bcode, dw);
  quant_out<<<2560, 256, 0, stream>>>(ema, dw, counts, hist, idxb, q_out,
                                      sxqp, sqqp);
  loss_final<<<1, 256, 0, stream>>>(sxxp, sxqp, sqqp, loss_out);
}